// Round 10
// baseline (3156.138 us; speedup 1.0000x reference)
//
#include <hip/hip_runtime.h>
#include <hip/hip_bf16.h>
#include <math.h>

#define NH 6
#define DKk 256
#define DVv 512
#define HIDDIM 2048
#define TT 4096
#define NBb 2
#define MTOK (NBb*TT)   // 8192
#define CH 64
#define NCH (TT/CH)     // 64 chunks per sequence
#define SCLN 136

typedef __hip_bfloat16 bf16;
typedef __attribute__((ext_vector_type(8))) short bf16x8;
typedef __attribute__((ext_vector_type(4))) float f32x4;

union FragU { bf16x8 v; uint2 u2[2]; uint4 u4; };
union BfBits { bf16 h; unsigned short s; };
union U4S8 { uint4 u; unsigned short s[8]; };

__device__ inline float bflo(unsigned u) { return __uint_as_float(u << 16); }
__device__ inline float bfhi(unsigned u) { return __uint_as_float(u & 0xffff0000u); }
__device__ inline unsigned short bfbits(float f) {
    BfBits b; b.h = __float2bfloat16(f); return b.s;
}
__device__ inline float bf2f(unsigned short s) { return __uint_as_float(((unsigned)s) << 16); }
__device__ inline uint4 pack8(float4 a, float4 b) {
    U4S8 r;
    r.s[0] = bfbits(a.x); r.s[1] = bfbits(a.y); r.s[2] = bfbits(a.z); r.s[3] = bfbits(a.w);
    r.s[4] = bfbits(b.x); r.s[5] = bfbits(b.y); r.s[6] = bfbits(b.z); r.s[7] = bfbits(b.w);
    return r.u;
}
// pack two f32x4 C-tiles (same lane) into a bf16x8 B-frag (C-tile->B-frag identity)
__device__ inline bf16x8 pk8t(f32x4 a, f32x4 b) {
    U4S8 r;
    r.s[0] = bfbits(a[0]); r.s[1] = bfbits(a[1]); r.s[2] = bfbits(a[2]); r.s[3] = bfbits(a[3]);
    r.s[4] = bfbits(b[0]); r.s[5] = bfbits(b[1]); r.s[6] = bfbits(b[2]); r.s[7] = bfbits(b[3]);
    FragU f; f.u4 = r.u; return f.v;
}

// LDS tile stride 256 elems, XOR-swizzled by ((row&7)<<4) on byte offset
__device__ inline bf16x8 lfrag256(const short* sh, int n0, int k0) {
    int lane = threadIdx.x & 63;
    int r = n0 + (lane & 15);
    int c = k0 + ((lane >> 4) * 4);
    FragU f;
    f.u2[0] = *(const uint2*)((const char*)sh + (((r * 256 + c) * 2) ^ ((r & 7) << 4)));
    f.u2[1] = *(const uint2*)((const char*)sh + (((r * 256 + c + 16) * 2) ^ ((r & 7) << 4)));
    return f.v;
}
// LDS tile stride 64 elems, swizzled
__device__ inline bf16x8 lfrag64(const short* sh, int n0, int k0) {
    int lane = threadIdx.x & 63;
    int r = n0 + (lane & 15);
    int c = k0 + ((lane >> 4) * 4);
    FragU f;
    f.u2[0] = *(const uint2*)((const char*)sh + (((r * 64 + c) * 2) ^ ((r & 7) << 4)));
    f.u2[1] = *(const uint2*)((const char*)sh + (((r * 64 + c + 16) * 2) ^ ((r & 7) << 4)));
    return f.v;
}
// LDS tile stride 72 elems (padded), no swizzle
__device__ inline bf16x8 lfrag72(const short* sh, int n0, int k0) {
    int lane = threadIdx.x & 63;
    int r = n0 + (lane & 15);
    int c = k0 + ((lane >> 4) * 4);
    FragU f;
    f.u2[0] = *(const uint2*)((const char*)sh + (r * 72 + c) * 2);
    f.u2[1] = *(const uint2*)((const char*)sh + (r * 72 + c + 16) * 2);
    return f.v;
}
// A-frag from f32 [64][68] LDS, scaled per-column, cvt to bf16
__device__ inline bf16x8 mfrag(const float* Msh, const float* colscale, int m0, int k0) {
    int lane = threadIdx.x & 63;
    int t = m0 + (lane & 15);
    int s0 = k0 + ((lane >> 4) * 4);
    U4S8 r;
#pragma unroll
    for (int i = 0; i < 4; ++i) {
        r.s[i]     = bfbits(Msh[t * 68 + s0 + i]      * colscale[s0 + i]);
        r.s[4 + i] = bfbits(Msh[t * 68 + s0 + 16 + i] * colscale[s0 + 16 + i]);
    }
    FragU f; f.u4 = r.u; return f.v;
}

// ---------------------------------------------------------------------------
// MFMA GEMM: C[m,n] = sum_k A[m,k]*B[n,k]; A: [M,K] (fp32 or bf16), B: [N,K]
// fp32. bf16 MFMA 16x16x32, fp32 accum. Tile 128x128xBK64, 4 waves.
// ---------------------------------------------------------------------------
template <typename TA, typename TC>
__global__ __launch_bounds__(256) void mfma_gemm_nt(const TA* __restrict__ A,
                                                    const float* __restrict__ B,
                                                    TC* __restrict__ C,
                                                    int M, int N, int K) {
    __shared__ __align__(16) short As[128 * 64];
    __shared__ __align__(16) short Bs[128 * 64];
    const int tid = threadIdx.x;
    const int lane = tid & 63;
    const int wid = tid >> 6;
    const int wr = wid >> 1, wc = wid & 1;
    const int bm = blockIdx.y * 128, bn = blockIdx.x * 128;
    const int srow = tid >> 1;
    const int sks = (tid & 1) * 32;

    f32x4 acc[4][4];
#pragma unroll
    for (int i = 0; i < 4; ++i)
#pragma unroll
        for (int j = 0; j < 4; ++j) acc[i][j] = f32x4{0.f, 0.f, 0.f, 0.f};

    auto swzb = [](int row, int kelem) {
        return ((row * 64 + kelem) * 2) ^ ((row & 7) << 4);
    };
    uint4 ra[4], rb[4];
    auto fetch = [&](int k0) {
        if constexpr (sizeof(TA) == 2) {
            const uint4* pa = (const uint4*)(A + (size_t)(bm + srow) * K + k0 + sks);
#pragma unroll
            for (int j = 0; j < 4; ++j) ra[j] = pa[j];
        } else {
            const float4* pa = (const float4*)(A + (size_t)(bm + srow) * K + k0 + sks);
#pragma unroll
            for (int j = 0; j < 4; ++j) ra[j] = pack8(pa[2 * j], pa[2 * j + 1]);
        }
        const float4* pb = (const float4*)(B + (size_t)(bn + srow) * K + k0 + sks);
#pragma unroll
        for (int j = 0; j < 4; ++j) rb[j] = pack8(pb[2 * j], pb[2 * j + 1]);
    };
    auto store_lds = [&]() {
#pragma unroll
        for (int j = 0; j < 4; ++j) {
            int byte = swzb(srow, sks + 8 * j);
            *(uint4*)((char*)As + byte) = ra[j];
            *(uint4*)((char*)Bs + byte) = rb[j];
        }
    };
    auto rdfrag = [&](const short* Sm, int row, int kbase) {
        FragU f;
        int ko = kbase + (lane >> 4) * 4;
        f.u2[0] = *(const uint2*)((const char*)Sm + swzb(row, ko));
        f.u2[1] = *(const uint2*)((const char*)Sm + swzb(row, ko + 16));
        return f.v;
    };

    fetch(0);
    for (int k0 = 0; k0 < K; k0 += 64) {
        __syncthreads();
        store_lds();
        __syncthreads();
        if (k0 + 64 < K) fetch(k0 + 64);
#pragma unroll
        for (int kk = 0; kk < 2; ++kk) {
            bf16x8 af[4], bfr[4];
#pragma unroll
            for (int i = 0; i < 4; ++i)
                af[i] = rdfrag(As, wr * 64 + i * 16 + (lane & 15), kk * 32);
#pragma unroll
            for (int j = 0; j < 4; ++j)
                bfr[j] = rdfrag(Bs, wc * 64 + j * 16 + (lane & 15), kk * 32);
#pragma unroll
            for (int i = 0; i < 4; ++i)
#pragma unroll
                for (int j = 0; j < 4; ++j)
                    acc[i][j] = __builtin_amdgcn_mfma_f32_16x16x32_bf16(
                        af[i], bfr[j], acc[i][j], 0, 0, 0);
        }
    }
#pragma unroll
    for (int i = 0; i < 4; ++i)
#pragma unroll
        for (int j = 0; j < 4; ++j) {
            int row = bm + wr * 64 + i * 16 + (lane >> 4) * 4;
            int col = bn + wc * 64 + j * 16 + (lane & 15);
#pragma unroll
            for (int qi = 0; qi < 4; ++qi) {
                float vv = acc[i][j][qi];
                if constexpr (sizeof(TC) == 2)
                    C[(size_t)(row + qi) * N + col] = __float2bfloat16(vv);
                else
                    C[(size_t)(row + qi) * N + col] = vv;
            }
        }
}

// ---------------------------------------------------------------------------
// causal depthwise conv4 + SiLU + per-head l2norm (+scale) for q/k.
// ---------------------------------------------------------------------------
__global__ __launch_bounds__(256) void convnorm_qk(const bf16* __restrict__ pre,
                                                   const float* __restrict__ cw,
                                                   bf16* __restrict__ out,
                                                   float scale) {
    const int bth = blockIdx.x;
    const int h = bth % NH;
    const int bt = bth / NH;
    const int t = bt % TT;
    const int d = threadIdx.x;
    const int c = h * DKk + d;
    const int C = NH * DKk;
    const bf16* p = pre + (size_t)bt * C + c;

    float w0 = cw[c * 4 + 0], w1 = cw[c * 4 + 1], w2 = cw[c * 4 + 2], w3 = cw[c * 4 + 3];
    float y = w3 * __bfloat162float(p[0]);
    if (t >= 1) y = fmaf(w2, __bfloat162float(p[-(ptrdiff_t)C]), y);
    if (t >= 2) y = fmaf(w1, __bfloat162float(p[-(ptrdiff_t)(2 * C)]), y);
    if (t >= 3) y = fmaf(w0, __bfloat162float(p[-(ptrdiff_t)(3 * C)]), y);
    y = y / (1.f + expf(-y));   // SiLU

    float s = y * y;
#pragma unroll
    for (int off = 32; off >= 1; off >>= 1) s += __shfl_down(s, off, 64);
    __shared__ float red[4];
    if ((threadIdx.x & 63) == 0) red[threadIdx.x >> 6] = s;
    __syncthreads();
    float tot = (red[0] + red[1]) + (red[2] + red[3]);
    out[(size_t)bt * C + c] = __float2bfloat16(y * rsqrtf(tot + 1e-6f) * scale);
}

// ---------------------------------------------------------------------------
// causal depthwise conv4 + SiLU for v.
// ---------------------------------------------------------------------------
__global__ __launch_bounds__(256) void conv_v_kernel(const bf16* __restrict__ pre,
                                                     const float* __restrict__ cw,
                                                     bf16* __restrict__ out) {
    const int C = NH * DVv;
    int idx = blockIdx.x * 256 + threadIdx.x;
    int c = idx % C;
    int bt = idx / C;
    int t = bt % TT;
    const bf16* p = pre + (size_t)bt * C + c;
    float y = cw[c * 4 + 3] * __bfloat162float(p[0]);
    if (t >= 1) y = fmaf(cw[c * 4 + 2], __bfloat162float(p[-(ptrdiff_t)C]), y);
    if (t >= 2) y = fmaf(cw[c * 4 + 1], __bfloat162float(p[-(ptrdiff_t)(2 * C)]), y);
    if (t >= 3) y = fmaf(cw[c * 4 + 0], __bfloat162float(p[-(ptrdiff_t)(3 * C)]), y);
    out[(size_t)bt * C + c] = __float2bfloat16(y / (1.f + expf(-y)));
}

// ---------------------------------------------------------------------------
// beta = sigmoid(x@Wb.T), g = -exp(A_log)*softplus(x@Wa.T + dt_bias)
// ---------------------------------------------------------------------------
__global__ __launch_bounds__(256) void proj_ab(const float* __restrict__ x,
                                               const float* __restrict__ Wb,
                                               const float* __restrict__ Wa,
                                               const float* __restrict__ A_log,
                                               const float* __restrict__ dt_bias,
                                               float* __restrict__ beta,
                                               float* __restrict__ g) {
    const int bt = blockIdx.x;
    const int tid = threadIdx.x;
    const float* xr = x + (size_t)bt * HIDDIM;
    float accb[NH], acca[NH];
#pragma unroll
    for (int h = 0; h < NH; ++h) { accb[h] = 0.f; acca[h] = 0.f; }
    for (int k0 = tid; k0 < HIDDIM; k0 += 256) {
        float xv = xr[k0];
#pragma unroll
        for (int h = 0; h < NH; ++h) {
            accb[h] = fmaf(xv, Wb[h * HIDDIM + k0], accb[h]);
            acca[h] = fmaf(xv, Wa[h * HIDDIM + k0], acca[h]);
        }
    }
#pragma unroll
    for (int h = 0; h < NH; ++h) {
#pragma unroll
        for (int off = 32; off >= 1; off >>= 1) {
            accb[h] += __shfl_down(accb[h], off, 64);
            acca[h] += __shfl_down(acca[h], off, 64);
        }
    }
    __shared__ float redb[NH][4], reda[NH][4];
    int wv = tid >> 6;
    if ((tid & 63) == 0) {
#pragma unroll
        for (int h = 0; h < NH; ++h) { redb[h][wv] = accb[h]; reda[h][wv] = acca[h]; }
    }
    __syncthreads();
    if (tid < NH) {
        float sb = (redb[tid][0] + redb[tid][1]) + (redb[tid][2] + redb[tid][3]);
        float sa = (reda[tid][0] + reda[tid][1]) + (reda[tid][2] + reda[tid][3]);
        beta[(size_t)bt * NH + tid] = 1.f / (1.f + expf(-sb));
        float xg = sa + dt_bias[tid];
        float sp = fmaxf(xg, 0.f) + log1pf(expf(-fabsf(xg)));
        g[(size_t)bt * NH + tid] = -expf(A_log[tid]) * sp;
    }
}

// ---------------------------------------------------------------------------
// CHUNK PREP (parallel over all 768 (b,h,chunk)) — unchanged.
// ---------------------------------------------------------------------------
__global__ __launch_bounds__(256) void chunk_prep(const bf16* __restrict__ qbuf,
                                                  const bf16* __restrict__ kbuf,
                                                  bf16* __restrict__ vbuf,
                                                  bf16* __restrict__ tvbuf,
                                                  const float* __restrict__ gbuf,
                                                  const float* __restrict__ bbuf,
                                                  bf16* __restrict__ Bmat,
                                                  float* __restrict__ scl) {
    __shared__ __align__(16) short Ksh[64 * 256];
    __shared__ __align__(16) short Qsh[64 * 256];   // later: K_T [256][64]
    __shared__ __align__(16) float Ash[64 * 68];    // A, then M (in place)
    __shared__ __align__(16) short Vt[128 * 72];
    __shared__ float Lsh[64], betash[64], lamsh[64], blamsh[64];

    const int blk = blockIdx.x;
    const int c = blk % NCH;
    const int hh = (blk / NCH) % NH;
    const int b = blk / (NCH * NH);
    const int tid = threadIdx.x;
    const int wid = tid >> 6;
    const int lane = tid & 63;
    const int bt0 = b * TT + c * CH;
    const int cid = (b * NH + hh) * NCH + c;

    // stage K,Q (swizzled)
    {
        int r = tid >> 2, c0 = (tid & 3) * 64;
        const uint4* kg = (const uint4*)(kbuf + (size_t)(bt0 + r) * 1536 + hh * 256 + c0);
        const uint4* qg = (const uint4*)(qbuf + (size_t)(bt0 + r) * 1536 + hh * 256 + c0);
#pragma unroll
        for (int j = 0; j < 8; ++j) {
            int byte = ((r * 256 + c0 + j * 8) * 2) ^ ((r & 7) << 4);
            *(uint4*)((char*)Ksh + byte) = kg[j];
            *(uint4*)((char*)Qsh + byte) = qg[j];
        }
    }
    if (tid < 64) {
        float gv = gbuf[(size_t)(bt0 + tid) * NH + hh];
        float bv = bbuf[(size_t)(bt0 + tid) * NH + hh];
        float L = gv;
#pragma unroll
        for (int off = 1; off < 64; off <<= 1) {
            float o = __shfl_up(L, off, 64);
            if (lane >= off) L += o;
        }
        float L63 = __shfl(L, 63, 64);
        float lam = expf(L);
        Lsh[tid] = L; betash[tid] = bv; lamsh[tid] = lam; blamsh[tid] = bv * lam;
        scl[(size_t)cid * SCLN + tid] = expf(L63 - L);
        scl[(size_t)cid * SCLN + 68 + tid] = lam;
        if (tid == 63) scl[(size_t)cid * SCLN + 64] = lam;  // LamC = e^{L63}
    }
    __syncthreads();

    // KK^T and QK^T
    f32x4 akk[4], aqk[4];
#pragma unroll
    for (int n = 0; n < 4; ++n) { akk[n] = f32x4{0,0,0,0}; aqk[n] = f32x4{0,0,0,0}; }
#pragma unroll
    for (int kk = 0; kk < 8; ++kk) {
        bf16x8 aK = lfrag256(Ksh, wid * 16, kk * 32);
        bf16x8 aQ = lfrag256(Qsh, wid * 16, kk * 32);
#pragma unroll
        for (int n = 0; n < 4; ++n) {
            bf16x8 bK = lfrag256(Ksh, n * 16, kk * 32);
            akk[n] = __builtin_amdgcn_mfma_f32_16x16x32_bf16(aK, bK, akk[n], 0, 0, 0);
            aqk[n] = __builtin_amdgcn_mfma_f32_16x16x32_bf16(aQ, bK, aqk[n], 0, 0, 0);
        }
    }
    // A_mat + B_mat (C layout: row=(lane>>4)*4+qi, col=lane&15)
#pragma unroll
    for (int n = 0; n < 4; ++n)
#pragma unroll
        for (int qi = 0; qi < 4; ++qi) {
            int i = wid * 16 + (lane >> 4) * 4 + qi;
            int s = n * 16 + (lane & 15);
            float av = 0.f, bvv = 0.f;
            if (s <= i) {
                float sc2 = expf(Lsh[i] - Lsh[s]);
                if (s < i) av = betash[i] * sc2 * akk[n][qi];
                bvv = sc2 * aqk[n][qi];
            }
            Ash[i * 68 + s] = av;
            Bmat[(size_t)cid * 4096 + i * 64 + s] = __float2bfloat16(bvv);
        }
    __syncthreads();

    // solve M = (I+A)^-1 (wave 0, lane = column)
    if (wid == 0) {
        float mm[64];
        mm[0] = (lane == 0) ? 1.f : 0.f;
#pragma unroll
        for (int t = 1; t < 64; ++t) {
            float a0 = 0.f, a1 = 0.f, a2 = 0.f, a3 = 0.f;
#pragma unroll
            for (int s = 0; s < t; ++s) {
                float Av = Ash[t * 68 + s];
                if ((s & 3) == 0) a0 = fmaf(Av, mm[s], a0);
                else if ((s & 3) == 1) a1 = fmaf(Av, mm[s], a1);
                else if ((s & 3) == 2) a2 = fmaf(Av, mm[s], a2);
                else a3 = fmaf(Av, mm[s], a3);
            }
            mm[t] = ((t == lane) ? 1.f : 0.f) - ((a0 + a1) + (a2 + a3));
        }
#pragma unroll
        for (int t = 0; t < 64; ++t) Ash[t * 68 + lane] = mm[t];
    }
    __syncthreads();

    // Tv = M(bV) in 4 d-quarters of 128
    for (int q = 0; q < 4; ++q) {
        {   // stage V quarter transposed: Vt[d][i]
            int i = tid >> 2, d0 = (tid & 3) * 32;
            const uint4* vg = (const uint4*)(vbuf + (size_t)(bt0 + i) * 3072 + hh * 512 + q * 128 + d0);
#pragma unroll
            for (int jb = 0; jb < 4; ++jb) {
                U4S8 u; u.u = vg[jb];
#pragma unroll
                for (int e = 0; e < 8; ++e)
                    Vt[(d0 + jb * 8 + e) * 72 + i] = (short)u.s[e];
            }
        }
        __syncthreads();
        f32x4 acc[8];
#pragma unroll
        for (int n = 0; n < 8; ++n) acc[n] = f32x4{0,0,0,0};
#pragma unroll
        for (int kk = 0; kk < 2; ++kk) {
            bf16x8 am = mfrag(Ash, betash, wid * 16, kk * 32);
#pragma unroll
            for (int n = 0; n < 8; ++n) {
                bf16x8 bv8 = lfrag72(Vt, n * 16, kk * 32);
                acc[n] = __builtin_amdgcn_mfma_f32_16x16x32_bf16(am, bv8, acc[n], 0, 0, 0);
            }
        }
#pragma unroll
        for (int n = 0; n < 8; ++n)
#pragma unroll
            for (int qi = 0; qi < 4; ++qi) {
                int t = wid * 16 + (lane >> 4) * 4 + qi;
                int d = q * 128 + n * 16 + (lane & 15);
                tvbuf[(size_t)(bt0 + t) * 3072 + hh * 512 + d] = __float2bfloat16(acc[n][qi]);
            }
        __syncthreads();
    }

    // build K_T [256][64] into Qsh (swizzled)
    {
        int j = tid;
        unsigned short rowv[64];
#pragma unroll
        for (int s = 0; s < 64; ++s)
            rowv[s] = *(const unsigned short*)((const char*)Ksh + (((s * 256 + j) * 2) ^ ((s & 7) << 4)));
#pragma unroll
        for (int sb = 0; sb < 8; ++sb) {
            U4S8 u;
#pragma unroll
            for (int e = 0; e < 8; ++e) u.s[e] = rowv[sb * 8 + e];
            *(uint4*)((char*)Qsh + (((j * 64 + sb * 8) * 2) ^ ((j & 7) << 4))) = u.u;
        }
    }
    __syncthreads();

    // Tk = M(b.Lam.K): A = M*blam, B = K_T
    {
        f32x4 acc[16];
#pragma unroll
        for (int n = 0; n < 16; ++n) acc[n] = f32x4{0,0,0,0};
#pragma unroll
        for (int kk = 0; kk < 2; ++kk) {
            bf16x8 am = mfrag(Ash, blamsh, wid * 16, kk * 32);
#pragma unroll
            for (int n = 0; n < 16; ++n) {
                bf16x8 bk = lfrag64(Qsh, n * 16, kk * 32);
                acc[n] = __builtin_amdgcn_mfma_f32_16x16x32_bf16(am, bk, acc[n], 0, 0, 0);
            }
        }
#pragma unroll
        for (int n = 0; n < 16; ++n)
#pragma unroll
            for (int qi = 0; qi < 4; ++qi) {
                int t = wid * 16 + (lane >> 4) * 4 + qi;
                int j = n * 16 + (lane & 15);
                vbuf[(size_t)(bt0 + t) * 3072 + hh * 512 + j] = __float2bfloat16(acc[n][qi]);
            }
    }
    // flush K_T -> global segment layout: row i=j>>2 of chunk, cols 256 + (j&3)*64 + s
    {
        int j = tid;
#pragma unroll
        for (int sb = 0; sb < 8; ++sb) {
            uint4 u = *(uint4*)((char*)Qsh + (((j * 64 + sb * 8) * 2) ^ ((j & 7) << 4)));
            *(uint4*)(vbuf + (size_t)(bt0 + (j >> 2)) * 3072 + hh * 512 + 256 + (j & 3) * 64 + sb * 8) = u;
        }
    }
}

// ---------------------------------------------------------------------------
// CHUNK SCAN v4 — LDS-staged operands with SOFTWARE PIPELINE (T14 split).
// 48 blocks = 12 bh x 4 parts, 512 threads = 8 waves; wave w owns slice
// part*8+w. Per chunk: barrier -> WRITE(regs c -> LDS) -> issue Tv(c) loads
// -> barrier -> issue LOAD(c+1 -> regs) -> COMPUTE(c). The c+1 HBM latency
// hides under chunk c's MFMAs; Tv latency hides under the P/O MFMA block.
// ---------------------------------------------------------------------------
__global__ __launch_bounds__(512, 1) void chunk_scan4(const bf16* __restrict__ qbuf,
                                                      const bf16* __restrict__ vbuf,
                                                      bf16* __restrict__ tvbuf,
                                                      const bf16* __restrict__ Bmat,
                                                      const float* __restrict__ scl) {
    __shared__ __align__(16) short TkL[64 * 256];   // 32KB, lfrag256 layout
    __shared__ __align__(16) short QL[64 * 256];    // 32KB, lfrag256
    __shared__ __align__(16) short KTL[256 * 64];   // 32KB, lfrag64
    __shared__ __align__(16) short BmL[64 * 64];    // 8KB,  lfrag64
    const int tid = threadIdx.x;
    const int wid = tid >> 6;
    const int lane = tid & 63;
    const int part = blockIdx.x & 3;
    const int bh = blockIdx.x >> 2;
    const int hh = bh % NH;
    const int b = bh / NH;
    const int slice = part * 8 + wid;            // 0..31
    const int dglob0 = hh * 512 + slice * 16;
    const int tlo = (lane >> 4) * 4;
    const int dcol = lane & 15;

    // staging-index precompute
    const int sr = tid >> 3, sbc0 = (tid & 7) * 16;   // Tk/Q/Bm pattern
    const int sj = tid >> 1, sjb0 = (tid & 1) * 16;   // KT pattern

    uint4 rTk[4], rQ[4], rKT[4], rBm;
    auto load_ops = [&](int c2) {
        if (c2 < NCH) {
            const int bt = b * TT + c2 * CH;
            const int cid2 = (b * NH + hh) * NCH + c2;
#pragma unroll
            for (int rd = 0; rd < 4; ++rd) {
                int bc = sbc0 + rd * 128;
                rTk[rd] = *(const uint4*)((const char*)(vbuf) +
                    ((size_t)(bt + sr) * 3072 + hh * 512) * 2 + bc);
                rQ[rd] = *(const uint4*)((const char*)(qbuf) +
                    ((size_t)(bt + sr) * 1536 + hh * 256) * 2 + bc);
            }
#pragma unroll
            for (int rd = 0; rd < 4; ++rd) {
                int bc = sjb0 + rd * 32;
                rKT[rd] = *(const uint4*)((const char*)(vbuf) +
                    ((size_t)(bt + (sj >> 2)) * 3072 + hh * 512 + 256 + (sj & 3) * 64) * 2 + bc);
            }
            rBm = *(const uint4*)((const char*)(Bmat) +
                ((size_t)cid2 * 4096 + sr * 64) * 2 + sbc0);
        }
    };
    auto write_ops = [&]() {
#pragma unroll
        for (int rd = 0; rd < 4; ++rd) {
            int bc = sbc0 + rd * 128;
            int byte = (sr * 512 + bc) ^ ((sr & 7) << 4);
            *(uint4*)((char*)TkL + byte) = rTk[rd];
            *(uint4*)((char*)QL + byte) = rQ[rd];
        }
#pragma unroll
        for (int rd = 0; rd < 4; ++rd) {
            int bc = sjb0 + rd * 32;
            int byte = (sj * 128 + bc) ^ ((sj & 7) << 4);
            *(uint4*)((char*)KTL + byte) = rKT[rd];
        }
        {
            int byte = (sr * 128 + sbc0) ^ ((sr & 7) << 4);
            *(uint4*)((char*)BmL + byte) = rBm;
        }
    };

    f32x4 S[16];
#pragma unroll
    for (int i = 0; i < 16; ++i) S[i] = f32x4{0.f, 0.f, 0.f, 0.f};

    load_ops(0);
    for (int c = 0; c < NCH; ++c) {
        const int bt0 = b * TT + c * CH;
        const int cid = (b * NH + hh) * NCH + c;
        const float* sc = scl + (size_t)cid * SCLN;
        const float lamC = sc[64];

        __syncthreads();   // prior chunk's LDS reads complete
        write_ops();
        // issue Tv(c) loads early (consumed at U step, after 64 MFMAs)
        float tvp[4][4];
#pragma unroll
        for (int tf = 0; tf < 4; ++tf) {
            int t = tf * 16 + tlo;
#pragma unroll
            for (int qi = 0; qi < 4; ++qi)
                tvp[tf][qi] = __bfloat162float(
                    tvbuf[(size_t)(bt0 + t + qi) * 3072 + dglob0 + dcol]);
        }
        __syncthreads();
        load_ops(c + 1);   // issue next chunk's global loads (awaited next WRITE)

        // ---- per-wave register-only math ----
        bf16x8 sfr[8];
#pragma unroll
        for (int kk = 0; kk < 8; ++kk) sfr[kk] = pk8t(S[2 * kk], S[2 * kk + 1]);

        f32x4 P[4], O[4];
#pragma unroll
        for (int tf = 0; tf < 4; ++tf) { P[tf] = f32x4{0,0,0,0}; O[tf] = f32x4{0,0,0,0}; }
#pragma unroll
        for (int tf = 0; tf < 4; ++tf)
#pragma unroll
            for (int kk = 0; kk < 8; ++kk) {
                bf16x8 aT = lfrag256(TkL, tf * 16, kk * 32);
                bf16x8 aQ = lfrag256(QL, tf * 16, kk * 32);
                P[tf] = __builtin_amdgcn_mfma_f32_16x16x32_bf16(aT, sfr[kk], P[tf], 0, 0, 0);
                O[tf] = __builtin_amdgcn_mfma_f32_16x16x32_bf16(aQ, sfr[kk], O[tf], 0, 0, 0);
            }
        // O *= lam_t ; U = Tv - P (in place over P)
#pragma unroll
        for (int tf = 0; tf < 4; ++tf) {
            float4 lam4 = *(const float4*)(sc + 68 + tf * 16 + tlo);
            O[tf][0] *= lam4.x; O[tf][1] *= lam4.y; O[tf][2] *= lam4.z; O[tf][3] *= lam4.w;
#pragma unroll
            for (int qi = 0; qi < 4; ++qi)
                P[tf][qi] = tvp[tf][qi] - P[tf][qi];
        }
        bf16x8 ufr0 = pk8t(P[0], P[1]);
        bf16x8 ufr1 = pk8t(P[2], P[3]);
#pragma unroll
        for (int tf = 0; tf < 4; ++tf) {
            bf16x8 aB0 = lfrag64(BmL, tf * 16, 0);
            bf16x8 aB1 = lfrag64(BmL, tf * 16, 32);
            O[tf] = __builtin_amdgcn_mfma_f32_16x16x32_bf16(aB0, ufr0, O[tf], 0, 0, 0);
            O[tf] = __builtin_amdgcn_mfma_f32_16x16x32_bf16(aB1, ufr1, O[tf], 0, 0, 0);
            int t = tf * 16 + tlo;
#pragma unroll
            for (int qi = 0; qi < 4; ++qi)
                tvbuf[(size_t)(bt0 + t + qi) * 3072 + dglob0 + dcol] = __float2bfloat16(O[tf][qi]);
        }
        // Ut B-frags: eC_t o U
        bf16x8 utfr[2];
#pragma unroll
        for (int k2 = 0; k2 < 2; ++k2) {
            float4 e0 = *(const float4*)(sc + k2 * 32 + tlo);
            float4 e1 = *(const float4*)(sc + k2 * 32 + 16 + tlo);
            f32x4 ua = P[2 * k2], ub = P[2 * k2 + 1];
            ua[0] *= e0.x; ua[1] *= e0.y; ua[2] *= e0.z; ua[3] *= e0.w;
            ub[0] *= e1.x; ub[1] *= e1.y; ub[2] *= e1.z; ub[3] *= e1.w;
            utfr[k2] = pk8t(ua, ub);
        }
        // S = lamC*S + KT.(eC o U)
#pragma unroll
        for (int kt = 0; kt < 16; ++kt) {
            S[kt][0] *= lamC; S[kt][1] *= lamC; S[kt][2] *= lamC; S[kt][3] *= lamC;
        }
#pragma unroll
        for (int kt = 0; kt < 16; ++kt)
#pragma unroll
            for (int k2 = 0; k2 < 2; ++k2) {
                bf16x8 aK = lfrag64(KTL, kt * 16, k2 * 32);
                S[kt] = __builtin_amdgcn_mfma_f32_16x16x32_bf16(aK, utfr[k2], S[kt], 0, 0, 0);
            }
    }
}

// ---------------------------------------------------------------------------
// per-head RMSNorm (eps 1e-5) * norm_w, then * silu(gate). In-place (bf16).
// ---------------------------------------------------------------------------
__global__ __launch_bounds__(256) void rmsgate_kernel(bf16* __restrict__ o,
                                                      const bf16* __restrict__ gate,
                                                      const float* __restrict__ norm_w) {
    const int bhead = blockIdx.x;
    const int d = threadIdx.x;
    bf16* op = o + (size_t)bhead * DVv;
    const bf16* gp = gate + (size_t)bhead * DVv;
    float x0 = __bfloat162float(op[d]), x1 = __bfloat162float(op[d + 256]);
    float s = x0 * x0 + x1 * x1;
#pragma unroll
    for (int off = 32; off >= 1; off >>= 1) s += __shfl_down(s, off, 64);
    __shared__ float red[4];
    if ((threadIdx.x & 63) == 0) red[threadIdx.x >> 6] = s;
    __syncthreads();
    float tot = (red[0] + red[1]) + (red[2] + red[3]);
    float r = rsqrtf(tot * (1.f / DVv) + 1e-5f);
    float g0 = __bfloat162float(gp[d]), g1 = __bfloat162float(gp[d + 256]);
    g0 = g0 / (1.f + expf(-g0));
    g1 = g1 / (1.f + expf(-g1));
    op[d]       = __float2bfloat16(x0 * r * norm_w[d] * g0);
    op[d + 256] = __float2bfloat16(x1 * r * norm_w[d + 256] * g1);
}

__global__ void fill_kernel(float* p, int n, float v) {
    int i = blockIdx.x * 256 + threadIdx.x;
    if (i < n) p[i] = v;
}

// ---------------------------------------------------------------------------
extern "C" void kernel_launch(void* const* d_in, const int* in_sizes, int n_in,
                              void* d_out, int out_size, void* d_ws, size_t ws_size,
                              hipStream_t stream) {
    const float* x       = (const float*)d_in[0];
    const float* Wq      = (const float*)d_in[1];
    const float* Wk      = (const float*)d_in[2];
    const float* Wv      = (const float*)d_in[3];
    const float* Wb      = (const float*)d_in[4];
    const float* Wa      = (const float*)d_in[5];
    const float* A_log   = (const float*)d_in[6];
    const float* dt_bias = (const float*)d_in[7];
    const float* cwq     = (const float*)d_in[8];
    const float* cwk     = (const float*)d_in[9];
    const float* cwv     = (const float*)d_in[10];
    const float* Wg      = (const float*)d_in[11];
    const float* norm_w  = (const float*)d_in[12];
    const float* Wo      = (const float*)d_in[13];
    float* out = (float*)d_out;

    // d_out scratch: qb/kb ONLY (write-once-read-later, replay-proven).
    bf16* qb = (bf16*)d_out;                          // [8192,1536]
    bf16* kb = qb + (size_t)MTOK * 1536;              // [8192,1536]

    // ws: A = {preQ|preK | v -> Tk/K_T | gate}, B = {preV | Tv -> O},
    //     Bmat, scl, beta, g.
    const size_t elemsA = (size_t)MTOK * 3072;
    const size_t elemsB = (size_t)MTOK * 3072;
    bf16* wsA   = (bf16*)d_ws;
    bf16* wsB   = wsA + elemsA;
    bf16* Bmat  = wsB + elemsB;                       // [768][64][64]
    float* scl  = (float*)(Bmat + (size_t)NBb * NH * NCH * 4096);  // [768][136]
    float* betab = scl + (size_t)NBb * NH * NCH * SCLN;
    float* gb    = betab + (size_t)MTOK * NH;
    size_t need = ((size_t)(gb - (float*)d_ws) + (size_t)MTOK * NH) * sizeof(float);
    if (ws_size < need) {
        fill_kernel<<<(out_size + 255) / 256, 256, 0, stream>>>(out, out_size, 1e9f);
        return;
    }

    dim3 blk(256);
    // q projection -> conv+silu+l2norm (*DK^-0.5)
    mfma_gemm_nt<float, bf16><<<dim3(12, 64), blk, 0, stream>>>(x, Wq, wsA, MTOK, 1536, HIDDIM);
    convnorm_qk<<<MTOK * NH, dim3(DKk), 0, stream>>>(wsA, cwq, qb, 0.0625f);
    // k projection -> conv+silu+l2norm
    mfma_gemm_nt<float, bf16><<<dim3(12, 64), blk, 0, stream>>>(x, Wk, wsA, MTOK, 1536, HIDDIM);
    convnorm_qk<<<MTOK * NH, dim3(DKk), 0, stream>>>(wsA, cwk, kb, 1.0f);
    // v projection (into B) -> conv+silu (into A)
    mfma_gemm_nt<float, bf16><<<dim3(24, 64), blk, 0, stream>>>(x, Wv, wsB, MTOK, 3072, HIDDIM);
    conv_v_kernel<<<(MTOK * 3072) / 256, blk, 0, stream>>>(wsB, cwv, wsA);
    // beta / g
    proj_ab<<<MTOK, blk, 0, stream>>>(x, Wb, Wa, A_log, dt_bias, betab, gb);
    // chunked delta rule: prep (parallel) + scan v4 (pipelined LDS staging)
    chunk_prep<<<NBb * NH * NCH, blk, 0, stream>>>(qb, kb, wsA, wsB, gb, betab, Bmat, scl);
    chunk_scan4<<<NBb * NH * 4, dim3(512), 0, stream>>>(qb, wsA, wsB, Bmat, scl);
    // gate projection into A (Tk/K_T dead after scan)
    mfma_gemm_nt<float, bf16><<<dim3(24, 64), blk, 0, stream>>>(x, Wg, wsA, MTOK, 3072, HIDDIM);
    // rmsnorm + silu(gate), in place on O (wsB)
    rmsgate_kernel<<<MTOK * NH, blk, 0, stream>>>(wsB, wsA, norm_w);
    // output projection: O (bf16, wsB) x Wo (fp32) -> d_out fp32
    mfma_gemm_nt<bf16, float><<<dim3(16, 64), blk, 0, stream>>>(wsB, Wo, out, MTOK, 2048, 3072);
}

// Round 11
// 1848.246 us; speedup vs baseline: 1.7076x; 1.7076x over previous
//
#include <hip/hip_runtime.h>
#include <hip/hip_bf16.h>
#include <math.h>

#define NH 6
#define DKk 256
#define DVv 512
#define HIDDIM 2048
#define TT 4096
#define NBb 2
#define MTOK (NBb*TT)   // 8192
#define CH 64
#define NCH (TT/CH)     // 64 chunks per sequence
#define SCLN 136

typedef __hip_bfloat16 bf16;
typedef __attribute__((ext_vector_type(8))) short bf16x8;
typedef __attribute__((ext_vector_type(4))) float f32x4;

union FragU { bf16x8 v; uint2 u2[2]; uint4 u4; };
union BfBits { bf16 h; unsigned short s; };
union U4S8 { uint4 u; unsigned short s[8]; };

__device__ inline float bflo(unsigned u) { return __uint_as_float(u << 16); }
__device__ inline float bfhi(unsigned u) { return __uint_as_float(u & 0xffff0000u); }
__device__ inline unsigned short bfbits(float f) {
    BfBits b; b.h = __float2bfloat16(f); return b.s;
}
__device__ inline float bf2f(unsigned short s) { return __uint_as_float(((unsigned)s) << 16); }
__device__ inline uint4 pack8(float4 a, float4 b) {
    U4S8 r;
    r.s[0] = bfbits(a.x); r.s[1] = bfbits(a.y); r.s[2] = bfbits(a.z); r.s[3] = bfbits(a.w);
    r.s[4] = bfbits(b.x); r.s[5] = bfbits(b.y); r.s[6] = bfbits(b.z); r.s[7] = bfbits(b.w);
    return r.u;
}
__device__ inline uint2 packh4(float a, float b, float c, float d) {
    union { unsigned short s[4]; uint2 u; } r;
    r.s[0] = bfbits(a); r.s[1] = bfbits(b); r.s[2] = bfbits(c); r.s[3] = bfbits(d);
    return r.u;
}
// pack two f32x4 C-tiles (same lane) into a bf16x8 B-frag (C-tile->B-frag identity)
__device__ inline bf16x8 pk8t(f32x4 a, f32x4 b) {
    U4S8 r;
    r.s[0] = bfbits(a[0]); r.s[1] = bfbits(a[1]); r.s[2] = bfbits(a[2]); r.s[3] = bfbits(a[3]);
    r.s[4] = bfbits(b[0]); r.s[5] = bfbits(b[1]); r.s[6] = bfbits(b[2]); r.s[7] = bfbits(b[3]);
    FragU f; f.u4 = r.u; return f.v;
}

// async global->LDS, 16B per lane (LDS dest = wave-uniform base + lane*16)
typedef const __attribute__((address_space(1))) void* gas_ptr;
typedef __attribute__((address_space(3))) void* las_ptr;
__device__ inline void gld16(const void* g, void* s) {
    __builtin_amdgcn_global_load_lds((gas_ptr)g, (las_ptr)s, 16, 0, 0);
}

// LDS tile stride 256 elems, XOR-swizzled by ((row&7)<<4) on byte offset
__device__ inline bf16x8 lfrag256(const short* sh, int n0, int k0) {
    int lane = threadIdx.x & 63;
    int r = n0 + (lane & 15);
    int c = k0 + ((lane >> 4) * 4);
    FragU f;
    f.u2[0] = *(const uint2*)((const char*)sh + (((r * 256 + c) * 2) ^ ((r & 7) << 4)));
    f.u2[1] = *(const uint2*)((const char*)sh + (((r * 256 + c + 16) * 2) ^ ((r & 7) << 4)));
    return f.v;
}
// LDS tile stride 64 elems, swizzled
__device__ inline bf16x8 lfrag64(const short* sh, int n0, int k0) {
    int lane = threadIdx.x & 63;
    int r = n0 + (lane & 15);
    int c = k0 + ((lane >> 4) * 4);
    FragU f;
    f.u2[0] = *(const uint2*)((const char*)sh + (((r * 64 + c) * 2) ^ ((r & 7) << 4)));
    f.u2[1] = *(const uint2*)((const char*)sh + (((r * 64 + c + 16) * 2) ^ ((r & 7) << 4)));
    return f.v;
}
// LDS tile stride 72 elems (padded), no swizzle
__device__ inline bf16x8 lfrag72(const short* sh, int n0, int k0) {
    int lane = threadIdx.x & 63;
    int r = n0 + (lane & 15);
    int c = k0 + ((lane >> 4) * 4);
    FragU f;
    f.u2[0] = *(const uint2*)((const char*)sh + (r * 72 + c) * 2);
    f.u2[1] = *(const uint2*)((const char*)sh + (r * 72 + c + 16) * 2);
    return f.v;
}
// A-frag from f32 [64][68] LDS, scaled per-column, cvt to bf16
__device__ inline bf16x8 mfrag(const float* Msh, const float* colscale, int m0, int k0) {
    int lane = threadIdx.x & 63;
    int t = m0 + (lane & 15);
    int s0 = k0 + ((lane >> 4) * 4);
    U4S8 r;
#pragma unroll
    for (int i = 0; i < 4; ++i) {
        r.s[i]     = bfbits(Msh[t * 68 + s0 + i]      * colscale[s0 + i]);
        r.s[4 + i] = bfbits(Msh[t * 68 + s0 + 16 + i] * colscale[s0 + 16 + i]);
    }
    FragU f; f.u4 = r.u; return f.v;
}

// ---------------------------------------------------------------------------
// fp32 -> bf16 conversion (vectorized, grid-stride). n % 4 == 0.
// ---------------------------------------------------------------------------
__global__ __launch_bounds__(256) void cvt_bf16(const float* __restrict__ in,
                                                bf16* __restrict__ out, int n) {
    for (int i = (blockIdx.x * 256 + threadIdx.x) * 4; i < n; i += gridDim.x * 256 * 4) {
        float4 v = *(const float4*)(in + i);
        *(uint2*)(out + i) = packh4(v.x, v.y, v.z, v.w);
    }
}

// ---------------------------------------------------------------------------
// FAST GEMM (both operands bf16 in global): C[m,n] = sum_k A[m,k]*B[n,k].
// m97 structure: 128x128xBK64 tile, 4 waves, global_load_lds width-16 into
// LINEAR LDS [128][64], ds_read_b128 frags with contiguous-k permutation
// (k = (lane>>4)*8 + {0..7}, identical for A and B -> dot-product invariant).
// ---------------------------------------------------------------------------
template <typename TC>
__global__ __launch_bounds__(256) void mfma_gemm_bb(const bf16* __restrict__ A,
                                                    const bf16* __restrict__ B,
                                                    TC* __restrict__ C,
                                                    int M, int N, int K) {
    __shared__ __align__(16) short As[128 * 64];
    __shared__ __align__(16) short Bs[128 * 64];
    const int tid = threadIdx.x;
    const int lane = tid & 63;
    const int wid = tid >> 6;
    const int wr = wid >> 1, wc = wid & 1;
    const int bm = blockIdx.y * 128, bn = blockIdx.x * 128;

    f32x4 acc[4][4];
#pragma unroll
    for (int i = 0; i < 4; ++i)
#pragma unroll
        for (int j = 0; j < 4; ++j) acc[i][j] = f32x4{0.f, 0.f, 0.f, 0.f};

    for (int k0 = 0; k0 < K; k0 += 64) {
        __syncthreads();   // previous compute done before LDS overwrite
#pragma unroll
        for (int i = 0; i < 4; ++i) {
            int r0 = wid * 32 + i * 8;                 // wave-uniform row base
            const bf16* ga = A + (size_t)(bm + r0 + (lane >> 3)) * K + k0 + (lane & 7) * 8;
            const bf16* gb = B + (size_t)(bn + r0 + (lane >> 3)) * K + k0 + (lane & 7) * 8;
            gld16(ga, &As[r0 * 64]);
            gld16(gb, &Bs[r0 * 64]);
        }
        __syncthreads();   // compiler drains vmcnt before barrier -> tiles ready
#pragma unroll
        for (int kk = 0; kk < 2; ++kk) {
            bf16x8 af[4], bfr[4];
#pragma unroll
            for (int i = 0; i < 4; ++i) {
                FragU f;
                f.u4 = *(const uint4*)&As[(wr * 64 + i * 16 + (lane & 15)) * 64 +
                                          kk * 32 + (lane >> 4) * 8];
                af[i] = f.v;
            }
#pragma unroll
            for (int j = 0; j < 4; ++j) {
                FragU f;
                f.u4 = *(const uint4*)&Bs[(wc * 64 + j * 16 + (lane & 15)) * 64 +
                                          kk * 32 + (lane >> 4) * 8];
                bfr[j] = f.v;
            }
#pragma unroll
            for (int i = 0; i < 4; ++i)
#pragma unroll
                for (int j = 0; j < 4; ++j)
                    acc[i][j] = __builtin_amdgcn_mfma_f32_16x16x32_bf16(
                        af[i], bfr[j], acc[i][j], 0, 0, 0);
        }
    }
#pragma unroll
    for (int i = 0; i < 4; ++i)
#pragma unroll
        for (int j = 0; j < 4; ++j) {
            int row = bm + wr * 64 + i * 16 + (lane >> 4) * 4;
            int col = bn + wc * 64 + j * 16 + (lane & 15);
#pragma unroll
            for (int qi = 0; qi < 4; ++qi) {
                float vv = acc[i][j][qi];
                if constexpr (sizeof(TC) == 2)
                    C[(size_t)(row + qi) * N + col] = __float2bfloat16(vv);
                else
                    C[(size_t)(row + qi) * N + col] = vv;
            }
        }
}

// ---------------------------------------------------------------------------
// FALLBACK GEMM (fp32 B, reg-staged + pack) — round-9 proven.
// ---------------------------------------------------------------------------
template <typename TA, typename TC>
__global__ __launch_bounds__(256) void mfma_gemm_nt(const TA* __restrict__ A,
                                                    const float* __restrict__ B,
                                                    TC* __restrict__ C,
                                                    int M, int N, int K) {
    __shared__ __align__(16) short As[128 * 64];
    __shared__ __align__(16) short Bs[128 * 64];
    const int tid = threadIdx.x;
    const int lane = tid & 63;
    const int wid = tid >> 6;
    const int wr = wid >> 1, wc = wid & 1;
    const int bm = blockIdx.y * 128, bn = blockIdx.x * 128;
    const int srow = tid >> 1;
    const int sks = (tid & 1) * 32;

    f32x4 acc[4][4];
#pragma unroll
    for (int i = 0; i < 4; ++i)
#pragma unroll
        for (int j = 0; j < 4; ++j) acc[i][j] = f32x4{0.f, 0.f, 0.f, 0.f};

    auto swzb = [](int row, int kelem) {
        return ((row * 64 + kelem) * 2) ^ ((row & 7) << 4);
    };
    uint4 ra[4], rb[4];
    auto fetch = [&](int k0) {
        if constexpr (sizeof(TA) == 2) {
            const uint4* pa = (const uint4*)(A + (size_t)(bm + srow) * K + k0 + sks);
#pragma unroll
            for (int j = 0; j < 4; ++j) ra[j] = pa[j];
        } else {
            const float4* pa = (const float4*)(A + (size_t)(bm + srow) * K + k0 + sks);
#pragma unroll
            for (int j = 0; j < 4; ++j) ra[j] = pack8(pa[2 * j], pa[2 * j + 1]);
        }
        const float4* pb = (const float4*)(B + (size_t)(bn + srow) * K + k0 + sks);
#pragma unroll
        for (int j = 0; j < 4; ++j) rb[j] = pack8(pb[2 * j], pb[2 * j + 1]);
    };
    auto store_lds = [&]() {
#pragma unroll
        for (int j = 0; j < 4; ++j) {
            int byte = swzb(srow, sks + 8 * j);
            *(uint4*)((char*)As + byte) = ra[j];
            *(uint4*)((char*)Bs + byte) = rb[j];
        }
    };
    auto rdfrag = [&](const short* Sm, int row, int kbase) {
        FragU f;
        int ko = kbase + (lane >> 4) * 4;
        f.u2[0] = *(const uint2*)((const char*)Sm + swzb(row, ko));
        f.u2[1] = *(const uint2*)((const char*)Sm + swzb(row, ko + 16));
        return f.v;
    };

    fetch(0);
    for (int k0 = 0; k0 < K; k0 += 64) {
        __syncthreads();
        store_lds();
        __syncthreads();
        if (k0 + 64 < K) fetch(k0 + 64);
#pragma unroll
        for (int kk = 0; kk < 2; ++kk) {
            bf16x8 af[4], bfr[4];
#pragma unroll
            for (int i = 0; i < 4; ++i)
                af[i] = rdfrag(As, wr * 64 + i * 16 + (lane & 15), kk * 32);
#pragma unroll
            for (int j = 0; j < 4; ++j)
                bfr[j] = rdfrag(Bs, wc * 64 + j * 16 + (lane & 15), kk * 32);
#pragma unroll
            for (int i = 0; i < 4; ++i)
#pragma unroll
                for (int j = 0; j < 4; ++j)
                    acc[i][j] = __builtin_amdgcn_mfma_f32_16x16x32_bf16(
                        af[i], bfr[j], acc[i][j], 0, 0, 0);
        }
    }
#pragma unroll
    for (int i = 0; i < 4; ++i)
#pragma unroll
        for (int j = 0; j < 4; ++j) {
            int row = bm + wr * 64 + i * 16 + (lane >> 4) * 4;
            int col = bn + wc * 64 + j * 16 + (lane & 15);
#pragma unroll
            for (int qi = 0; qi < 4; ++qi) {
                float vv = acc[i][j][qi];
                if constexpr (sizeof(TC) == 2)
                    C[(size_t)(row + qi) * N + col] = __float2bfloat16(vv);
                else
                    C[(size_t)(row + qi) * N + col] = vv;
            }
        }
}

// ---------------------------------------------------------------------------
// causal depthwise conv4 + SiLU + per-head l2norm (+scale) for q/k.
// ---------------------------------------------------------------------------
__global__ __launch_bounds__(256) void convnorm_qk(const bf16* __restrict__ pre,
                                                   const float* __restrict__ cw,
                                                   bf16* __restrict__ out,
                                                   float scale) {
    const int bth = blockIdx.x;
    const int h = bth % NH;
    const int bt = bth / NH;
    const int t = bt % TT;
    const int d = threadIdx.x;
    const int c = h * DKk + d;
    const int C = NH * DKk;
    const bf16* p = pre + (size_t)bt * C + c;

    float w0 = cw[c * 4 + 0], w1 = cw[c * 4 + 1], w2 = cw[c * 4 + 2], w3 = cw[c * 4 + 3];
    float y = w3 * __bfloat162float(p[0]);
    if (t >= 1) y = fmaf(w2, __bfloat162float(p[-(ptrdiff_t)C]), y);
    if (t >= 2) y = fmaf(w1, __bfloat162float(p[-(ptrdiff_t)(2 * C)]), y);
    if (t >= 3) y = fmaf(w0, __bfloat162float(p[-(ptrdiff_t)(3 * C)]), y);
    y = y / (1.f + expf(-y));   // SiLU

    float s = y * y;
#pragma unroll
    for (int off = 32; off >= 1; off >>= 1) s += __shfl_down(s, off, 64);
    __shared__ float red[4];
    if ((threadIdx.x & 63) == 0) red[threadIdx.x >> 6] = s;
    __syncthreads();
    float tot = (red[0] + red[1]) + (red[2] + red[3]);
    out[(size_t)bt * C + c] = __float2bfloat16(y * rsqrtf(tot + 1e-6f) * scale);
}

// ---------------------------------------------------------------------------
// causal depthwise conv4 + SiLU for v.
// ---------------------------------------------------------------------------
__global__ __launch_bounds__(256) void conv_v_kernel(const bf16* __restrict__ pre,
                                                     const float* __restrict__ cw,
                                                     bf16* __restrict__ out) {
    const int C = NH * DVv;
    int idx = blockIdx.x * 256 + threadIdx.x;
    int c = idx % C;
    int bt = idx / C;
    int t = bt % TT;
    const bf16* p = pre + (size_t)bt * C + c;
    float y = cw[c * 4 + 3] * __bfloat162float(p[0]);
    if (t >= 1) y = fmaf(cw[c * 4 + 2], __bfloat162float(p[-(ptrdiff_t)C]), y);
    if (t >= 2) y = fmaf(cw[c * 4 + 1], __bfloat162float(p[-(ptrdiff_t)(2 * C)]), y);
    if (t >= 3) y = fmaf(cw[c * 4 + 0], __bfloat162float(p[-(ptrdiff_t)(3 * C)]), y);
    out[(size_t)bt * C + c] = __float2bfloat16(y / (1.f + expf(-y)));
}

// ---------------------------------------------------------------------------
// beta = sigmoid(x@Wb.T), g = -exp(A_log)*softplus(x@Wa.T + dt_bias)
// ---------------------------------------------------------------------------
__global__ __launch_bounds__(256) void proj_ab(const float* __restrict__ x,
                                               const float* __restrict__ Wb,
                                               const float* __restrict__ Wa,
                                               const float* __restrict__ A_log,
                                               const float* __restrict__ dt_bias,
                                               float* __restrict__ beta,
                                               float* __restrict__ g) {
    const int bt = blockIdx.x;
    const int tid = threadIdx.x;
    const float* xr = x + (size_t)bt * HIDDIM;
    float accb[NH], acca[NH];
#pragma unroll
    for (int h = 0; h < NH; ++h) { accb[h] = 0.f; acca[h] = 0.f; }
    for (int k0 = tid; k0 < HIDDIM; k0 += 256) {
        float xv = xr[k0];
#pragma unroll
        for (int h = 0; h < NH; ++h) {
            accb[h] = fmaf(xv, Wb[h * HIDDIM + k0], accb[h]);
            acca[h] = fmaf(xv, Wa[h * HIDDIM + k0], acca[h]);
        }
    }
#pragma unroll
    for (int h = 0; h < NH; ++h) {
#pragma unroll
        for (int off = 32; off >= 1; off >>= 1) {
            accb[h] += __shfl_down(accb[h], off, 64);
            acca[h] += __shfl_down(acca[h], off, 64);
        }
    }
    __shared__ float redb[NH][4], reda[NH][4];
    int wv = tid >> 6;
    if ((tid & 63) == 0) {
#pragma unroll
        for (int h = 0; h < NH; ++h) { redb[h][wv] = accb[h]; reda[h][wv] = acca[h]; }
    }
    __syncthreads();
    if (tid < NH) {
        float sb = (redb[tid][0] + redb[tid][1]) + (redb[tid][2] + redb[tid][3]);
        float sa = (reda[tid][0] + reda[tid][1]) + (reda[tid][2] + reda[tid][3]);
        beta[(size_t)bt * NH + tid] = 1.f / (1.f + expf(-sb));
        float xg = sa + dt_bias[tid];
        float sp = fmaxf(xg, 0.f) + log1pf(expf(-fabsf(xg)));
        g[(size_t)bt * NH + tid] = -expf(A_log[tid]) * sp;
    }
}

// ---------------------------------------------------------------------------
// CHUNK PREP (parallel over all 768 (b,h,chunk)) — unchanged.
// ---------------------------------------------------------------------------
__global__ __launch_bounds__(256) void chunk_prep(const bf16* __restrict__ qbuf,
                                                  const bf16* __restrict__ kbuf,
                                                  bf16* __restrict__ vbuf,
                                                  bf16* __restrict__ tvbuf,
                                                  const float* __restrict__ gbuf,
                                                  const float* __restrict__ bbuf,
                                                  bf16* __restrict__ Bmat,
                                                  float* __restrict__ scl) {
    __shared__ __align__(16) short Ksh[64 * 256];
    __shared__ __align__(16) short Qsh[64 * 256];   // later: K_T [256][64]
    __shared__ __align__(16) float Ash[64 * 68];    // A, then M (in place)
    __shared__ __align__(16) short Vt[128 * 72];
    __shared__ float Lsh[64], betash[64], lamsh[64], blamsh[64];

    const int blk = blockIdx.x;
    const int c = blk % NCH;
    const int hh = (blk / NCH) % NH;
    const int b = blk / (NCH * NH);
    const int tid = threadIdx.x;
    const int wid = tid >> 6;
    const int lane = tid & 63;
    const int bt0 = b * TT + c * CH;
    const int cid = (b * NH + hh) * NCH + c;

    // stage K,Q (swizzled)
    {
        int r = tid >> 2, c0 = (tid & 3) * 64;
        const uint4* kg = (const uint4*)(kbuf + (size_t)(bt0 + r) * 1536 + hh * 256 + c0);
        const uint4* qg = (const uint4*)(qbuf + (size_t)(bt0 + r) * 1536 + hh * 256 + c0);
#pragma unroll
        for (int j = 0; j < 8; ++j) {
            int byte = ((r * 256 + c0 + j * 8) * 2) ^ ((r & 7) << 4);
            *(uint4*)((char*)Ksh + byte) = kg[j];
            *(uint4*)((char*)Qsh + byte) = qg[j];
        }
    }
    if (tid < 64) {
        float gv = gbuf[(size_t)(bt0 + tid) * NH + hh];
        float bv = bbuf[(size_t)(bt0 + tid) * NH + hh];
        float L = gv;
#pragma unroll
        for (int off = 1; off < 64; off <<= 1) {
            float o = __shfl_up(L, off, 64);
            if (lane >= off) L += o;
        }
        float L63 = __shfl(L, 63, 64);
        float lam = expf(L);
        Lsh[tid] = L; betash[tid] = bv; lamsh[tid] = lam; blamsh[tid] = bv * lam;
        scl[(size_t)cid * SCLN + tid] = expf(L63 - L);
        scl[(size_t)cid * SCLN + 68 + tid] = lam;
        if (tid == 63) scl[(size_t)cid * SCLN + 64] = lam;  // LamC = e^{L63}
    }
    __syncthreads();

    // KK^T and QK^T
    f32x4 akk[4], aqk[4];
#pragma unroll
    for (int n = 0; n < 4; ++n) { akk[n] = f32x4{0,0,0,0}; aqk[n] = f32x4{0,0,0,0}; }
#pragma unroll
    for (int kk = 0; kk < 8; ++kk) {
        bf16x8 aK = lfrag256(Ksh, wid * 16, kk * 32);
        bf16x8 aQ = lfrag256(Qsh, wid * 16, kk * 32);
#pragma unroll
        for (int n = 0; n < 4; ++n) {
            bf16x8 bK = lfrag256(Ksh, n * 16, kk * 32);
            akk[n] = __builtin_amdgcn_mfma_f32_16x16x32_bf16(aK, bK, akk[n], 0, 0, 0);
            aqk[n] = __builtin_amdgcn_mfma_f32_16x16x32_bf16(aQ, bK, aqk[n], 0, 0, 0);
        }
    }
    // A_mat + B_mat (C layout: row=(lane>>4)*4+qi, col=lane&15)
#pragma unroll
    for (int n = 0; n < 4; ++n)
#pragma unroll
        for (int qi = 0; qi < 4; ++qi) {
            int i = wid * 16 + (lane >> 4) * 4 + qi;
            int s = n * 16 + (lane & 15);
            float av = 0.f, bvv = 0.f;
            if (s <= i) {
                float sc2 = expf(Lsh[i] - Lsh[s]);
                if (s < i) av = betash[i] * sc2 * akk[n][qi];
                bvv = sc2 * aqk[n][qi];
            }
            Ash[i * 68 + s] = av;
            Bmat[(size_t)cid * 4096 + i * 64 + s] = __float2bfloat16(bvv);
        }
    __syncthreads();

    // solve M = (I+A)^-1 (wave 0, lane = column)
    if (wid == 0) {
        float mm[64];
        mm[0] = (lane == 0) ? 1.f : 0.f;
#pragma unroll
        for (int t = 1; t < 64; ++t) {
            float a0 = 0.f, a1 = 0.f, a2 = 0.f, a3 = 0.f;
#pragma unroll
            for (int s = 0; s < t; ++s) {
                float Av = Ash[t * 68 + s];
                if ((s & 3) == 0) a0 = fmaf(Av, mm[s], a0);
                else if ((s & 3) == 1) a1 = fmaf(Av, mm[s], a1);
                else if ((s & 3) == 2) a2 = fmaf(Av, mm[s], a2);
                else a3 = fmaf(Av, mm[s], a3);
            }
            mm[t] = ((t == lane) ? 1.f : 0.f) - ((a0 + a1) + (a2 + a3));
        }
#pragma unroll
        for (int t = 0; t < 64; ++t) Ash[t * 68 + lane] = mm[t];
    }
    __syncthreads();

    // Tv = M(bV) in 4 d-quarters of 128
    for (int q = 0; q < 4; ++q) {
        {   // stage V quarter transposed: Vt[d][i]
            int i = tid >> 2, d0 = (tid & 3) * 32;
            const uint4* vg = (const uint4*)(vbuf + (size_t)(bt0 + i) * 3072 + hh * 512 + q * 128 + d0);
#pragma unroll
            for (int jb = 0; jb < 4; ++jb) {
                U4S8 u; u.u = vg[jb];
#pragma unroll
                for (int e = 0; e < 8; ++e)
                    Vt[(d0 + jb * 8 + e) * 72 + i] = (short)u.s[e];
            }
        }
        __syncthreads();
        f32x4 acc[8];
#pragma unroll
        for (int n = 0; n < 8; ++n) acc[n] = f32x4{0,0,0,0};
#pragma unroll
        for (int kk = 0; kk < 2; ++kk) {
            bf16x8 am = mfrag(Ash, betash, wid * 16, kk * 32);
#pragma unroll
            for (int n = 0; n < 8; ++n) {
                bf16x8 bv8 = lfrag72(Vt, n * 16, kk * 32);
                acc[n] = __builtin_amdgcn_mfma_f32_16x16x32_bf16(am, bv8, acc[n], 0, 0, 0);
            }
        }
#pragma unroll
        for (int n = 0; n < 8; ++n)
#pragma unroll
            for (int qi = 0; qi < 4; ++qi) {
                int t = wid * 16 + (lane >> 4) * 4 + qi;
                int d = q * 128 + n * 16 + (lane & 15);
                tvbuf[(size_t)(bt0 + t) * 3072 + hh * 512 + d] = __float2bfloat16(acc[n][qi]);
            }
        __syncthreads();
    }

    // build K_T [256][64] into Qsh (swizzled)
    {
        int j = tid;
        unsigned short rowv[64];
#pragma unroll
        for (int s = 0; s < 64; ++s)
            rowv[s] = *(const unsigned short*)((const char*)Ksh + (((s * 256 + j) * 2) ^ ((s & 7) << 4)));
#pragma unroll
        for (int sb = 0; sb < 8; ++sb) {
            U4S8 u;
#pragma unroll
            for (int e = 0; e < 8; ++e) u.s[e] = rowv[sb * 8 + e];
            *(uint4*)((char*)Qsh + (((j * 64 + sb * 8) * 2) ^ ((j & 7) << 4))) = u.u;
        }
    }
    __syncthreads();

    // Tk = M(b.Lam.K): A = M*blam, B = K_T
    {
        f32x4 acc[16];
#pragma unroll
        for (int n = 0; n < 16; ++n) acc[n] = f32x4{0,0,0,0};
#pragma unroll
        for (int kk = 0; kk < 2; ++kk) {
            bf16x8 am = mfrag(Ash, blamsh, wid * 16, kk * 32);
#pragma unroll
            for (int n = 0; n < 16; ++n) {
                bf16x8 bk = lfrag64(Qsh, n * 16, kk * 32);
                acc[n] = __builtin_amdgcn_mfma_f32_16x16x32_bf16(am, bk, acc[n], 0, 0, 0);
            }
        }
#pragma unroll
        for (int n = 0; n < 16; ++n)
#pragma unroll
            for (int qi = 0; qi < 4; ++qi) {
                int t = wid * 16 + (lane >> 4) * 4 + qi;
                int j = n * 16 + (lane & 15);
                vbuf[(size_t)(bt0 + t) * 3072 + hh * 512 + j] = __float2bfloat16(acc[n][qi]);
            }
    }
    // flush K_T -> global segment layout: row i=j>>2 of chunk, cols 256 + (j&3)*64 + s
    {
        int j = tid;
#pragma unroll
        for (int sb = 0; sb < 8; ++sb) {
            uint4 u = *(uint4*)((char*)Qsh + (((j * 64 + sb * 8) * 2) ^ ((j & 7) << 4)));
            *(uint4*)(vbuf + (size_t)(bt0 + (j >> 2)) * 3072 + hh * 512 + 256 + (j & 3) * 64 + sb * 8) = u;
        }
    }
}

// ---------------------------------------------------------------------------
// CHUNK SCAN v3 — LDS-staged operands, 8 waves/block (round-9 proven).
// ---------------------------------------------------------------------------
__global__ __launch_bounds__(512, 1) void chunk_scan3(const bf16* __restrict__ qbuf,
                                                      const bf16* __restrict__ vbuf,
                                                      bf16* __restrict__ tvbuf,
                                                      const bf16* __restrict__ Bmat,
                                                      const float* __restrict__ scl) {
    __shared__ __align__(16) short TkL[64 * 256];   // 32KB, lfrag256 layout
    __shared__ __align__(16) short QL[64 * 256];    // 32KB, lfrag256
    __shared__ __align__(16) short KTL[256 * 64];   // 32KB, lfrag64
    __shared__ __align__(16) short BmL[64 * 64];    // 8KB,  lfrag64
    const int tid = threadIdx.x;
    const int wid = tid >> 6;
    const int lane = tid & 63;
    const int part = blockIdx.x & 3;
    const int bh = blockIdx.x >> 2;
    const int hh = bh % NH;
    const int b = bh / NH;
    const int slice = part * 8 + wid;            // 0..31
    const int dglob0 = hh * 512 + slice * 16;
    const int tlo = (lane >> 4) * 4;
    const int dcol = lane & 15;

    f32x4 S[16];
#pragma unroll
    for (int i = 0; i < 16; ++i) S[i] = f32x4{0.f, 0.f, 0.f, 0.f};

    for (int c = 0; c < NCH; ++c) {
        const int bt0 = b * TT + c * CH;
        const int cid = (b * NH + hh) * NCH + c;
        const float* sc = scl + (size_t)cid * SCLN;
        const float lamC = sc[64];

        __syncthreads();   // prior chunk's LDS reads complete
        // ---- stage Tk (64x256, vbuf cols [0,256)) and Q (64x256, qbuf) ----
        {
            int r = tid >> 3;                    // 0..63
            int bc0 = (tid & 7) * 16;            // 16B lane within 128B group
#pragma unroll
            for (int rd = 0; rd < 4; ++rd) {
                int bc = bc0 + rd * 128;         // byte col in [0,512)
                uint4 tv = *(const uint4*)((const char*)(vbuf) +
                    ((size_t)(bt0 + r) * 3072 + hh * 512) * 2 + bc);
                uint4 qv = *(const uint4*)((const char*)(qbuf) +
                    ((size_t)(bt0 + r) * 1536 + hh * 256) * 2 + bc);
                int byte = (r * 512 + bc) ^ ((r & 7) << 4);
                *(uint4*)((char*)TkL + byte) = tv;
                *(uint4*)((char*)QL + byte) = qv;
            }
        }
        // ---- stage KT (256x64, vbuf cols [256,512) packed) ----
        {
            int j = tid >> 1;                    // 0..255
            int bc0 = (tid & 1) * 16;
#pragma unroll
            for (int rd = 0; rd < 4; ++rd) {
                int bc = bc0 + rd * 32;          // byte col in [0,128)
                uint4 v = *(const uint4*)((const char*)(vbuf) +
                    ((size_t)(bt0 + (j >> 2)) * 3072 + hh * 512 + 256 + (j & 3) * 64) * 2 + bc);
                int byte = (j * 128 + bc) ^ ((j & 7) << 4);
                *(uint4*)((char*)KTL + byte) = v;
            }
        }
        // ---- stage Bmat (64x64) ----
        {
            int r = tid >> 3;
            int bc = (tid & 7) * 16;
            uint4 v = *(const uint4*)((const char*)(Bmat) +
                ((size_t)cid * 4096 + r * 64) * 2 + bc);
            int byte = (r * 128 + bc) ^ ((r & 7) << 4);
            *(uint4*)((char*)BmL + byte) = v;
        }
        __syncthreads();

        // ---- per-wave register-only math ----
        bf16x8 sfr[8];
#pragma unroll
        for (int kk = 0; kk < 8; ++kk) sfr[kk] = pk8t(S[2 * kk], S[2 * kk + 1]);

        f32x4 P[4], O[4];
#pragma unroll
        for (int tf = 0; tf < 4; ++tf) { P[tf] = f32x4{0,0,0,0}; O[tf] = f32x4{0,0,0,0}; }
#pragma unroll
        for (int tf = 0; tf < 4; ++tf)
#pragma unroll
            for (int kk = 0; kk < 8; ++kk) {
                bf16x8 aT = lfrag256(TkL, tf * 16, kk * 32);
                bf16x8 aQ = lfrag256(QL, tf * 16, kk * 32);
                P[tf] = __builtin_amdgcn_mfma_f32_16x16x32_bf16(aT, sfr[kk], P[tf], 0, 0, 0);
                O[tf] = __builtin_amdgcn_mfma_f32_16x16x32_bf16(aQ, sfr[kk], O[tf], 0, 0, 0);
            }
        // O *= lam_t ; U = Tv - P (in place over P)
#pragma unroll
        for (int tf = 0; tf < 4; ++tf) {
            float4 lam4 = *(const float4*)(sc + 68 + tf * 16 + tlo);
            O[tf][0] *= lam4.x; O[tf][1] *= lam4.y; O[tf][2] *= lam4.z; O[tf][3] *= lam4.w;
            int t = tf * 16 + tlo;
#pragma unroll
            for (int qi = 0; qi < 4; ++qi) {
                float tv = __bfloat162float(tvbuf[(size_t)(bt0 + t + qi) * 3072 + dglob0 + dcol]);
                P[tf][qi] = tv - P[tf][qi];
            }
        }
        bf16x8 ufr0 = pk8t(P[0], P[1]);
        bf16x8 ufr1 = pk8t(P[2], P[3]);
#pragma unroll
        for (int tf = 0; tf < 4; ++tf) {
            bf16x8 aB0 = lfrag64(BmL, tf * 16, 0);
            bf16x8 aB1 = lfrag64(BmL, tf * 16, 32);
            O[tf] = __builtin_amdgcn_mfma_f32_16x16x32_bf16(aB0, ufr0, O[tf], 0, 0, 0);
            O[tf] = __builtin_amdgcn_mfma_f32_16x16x32_bf16(aB1, ufr1, O[tf], 0, 0, 0);
            int t = tf * 16 + tlo;
#pragma unroll
            for (int qi = 0; qi < 4; ++qi)
                tvbuf[(size_t)(bt0 + t + qi) * 3072 + dglob0 + dcol] = __float2bfloat16(O[tf][qi]);
        }
        // Ut B-frags: eC_t o U
        bf16x8 utfr[2];
#pragma unroll
        for (int k2 = 0; k2 < 2; ++k2) {
            float4 e0 = *(const float4*)(sc + k2 * 32 + tlo);
            float4 e1 = *(const float4*)(sc + k2 * 32 + 16 + tlo);
            f32x4 ua = P[2 * k2], ub = P[2 * k2 + 1];
            ua[0] *= e0.x; ua[1] *= e0.y; ua[2] *= e0.z; ua[3] *= e0.w;
            ub[0] *= e1.x; ub[1] *= e1.y; ub[2] *= e1.z; ub[3] *= e1.w;
            utfr[k2] = pk8t(ua, ub);
        }
        // S = lamC*S + KT.(eC o U)
#pragma unroll
        for (int kt = 0; kt < 16; ++kt) {
            S[kt][0] *= lamC; S[kt][1] *= lamC; S[kt][2] *= lamC; S[kt][3] *= lamC;
        }
#pragma unroll
        for (int kt = 0; kt < 16; ++kt)
#pragma unroll
            for (int k2 = 0; k2 < 2; ++k2) {
                bf16x8 aK = lfrag64(KTL, kt * 16, k2 * 32);
                S[kt] = __builtin_amdgcn_mfma_f32_16x16x32_bf16(aK, utfr[k2], S[kt], 0, 0, 0);
            }
    }
}

// ---------------------------------------------------------------------------
// per-head RMSNorm (eps 1e-5) * norm_w, then * silu(gate). In-place (bf16).
// ---------------------------------------------------------------------------
__global__ __launch_bounds__(256) void rmsgate_kernel(bf16* __restrict__ o,
                                                      const bf16* __restrict__ gate,
                                                      const float* __restrict__ norm_w) {
    const int bhead = blockIdx.x;
    const int d = threadIdx.x;
    bf16* op = o + (size_t)bhead * DVv;
    const bf16* gp = gate + (size_t)bhead * DVv;
    float x0 = __bfloat162float(op[d]), x1 = __bfloat162float(op[d + 256]);
    float s = x0 * x0 + x1 * x1;
#pragma unroll
    for (int off = 32; off >= 1; off >>= 1) s += __shfl_down(s, off, 64);
    __shared__ float red[4];
    if ((threadIdx.x & 63) == 0) red[threadIdx.x >> 6] = s;
    __syncthreads();
    float tot = (red[0] + red[1]) + (red[2] + red[3]);
    float r = rsqrtf(tot * (1.f / DVv) + 1e-5f);
    float g0 = __bfloat162float(gp[d]), g1 = __bfloat162float(gp[d + 256]);
    g0 = g0 / (1.f + expf(-g0));
    g1 = g1 / (1.f + expf(-g1));
    op[d]       = __float2bfloat16(x0 * r * norm_w[d] * g0);
    op[d + 256] = __float2bfloat16(x1 * r * norm_w[d + 256] * g1);
}

__global__ void fill_kernel(float* p, int n, float v) {
    int i = blockIdx.x * 256 + threadIdx.x;
    if (i < n) p[i] = v;
}

// ---------------------------------------------------------------------------
extern "C" void kernel_launch(void* const* d_in, const int* in_sizes, int n_in,
                              void* d_out, int out_size, void* d_ws, size_t ws_size,
                              hipStream_t stream) {
    const float* x       = (const float*)d_in[0];
    const float* Wq      = (const float*)d_in[1];
    const float* Wk      = (const float*)d_in[2];
    const float* Wv      = (const float*)d_in[3];
    const float* Wb      = (const float*)d_in[4];
    const float* Wa      = (const float*)d_in[5];
    const float* A_log   = (const float*)d_in[6];
    const float* dt_bias = (const float*)d_in[7];
    const float* cwq     = (const float*)d_in[8];
    const float* cwk     = (const float*)d_in[9];
    const float* cwv     = (const float*)d_in[10];
    const float* Wg      = (const float*)d_in[11];
    const float* norm_w  = (const float*)d_in[12];
    const float* Wo      = (const float*)d_in[13];
    float* out = (float*)d_out;

    // d_out scratch: qb/kb ONLY (write-once-read-later, replay-proven).
    bf16* qb = (bf16*)d_out;                          // [8192,1536]
    bf16* kb = qb + (size_t)MTOK * 1536;              // [8192,1536]

    // ws base layout (round-9 proven):
    const size_t elemsA = (size_t)MTOK * 3072;
    const size_t elemsB = (size_t)MTOK * 3072;
    bf16* wsA   = (bf16*)d_ws;
    bf16* wsB   = wsA + elemsA;
    bf16* Bmat  = wsB + elemsB;                       // [768][64][64]
    float* scl  = (float*)(Bmat + (size_t)NBb * NH * NCH * 4096);  // [768][136]
    float* betab = scl + (size_t)NBb * NH * NCH * SCLN;
    float* gb    = betab + (size_t)MTOK * NH;
    size_t need_base = ((size_t)(gb - (float*)d_ws) + (size_t)MTOK * NH) * sizeof(float);
    // fast-path extras: bf16 x + one shared weight slot (lifetimes disjoint)
    bf16* xb    = (bf16*)(gb + (size_t)MTOK * NH);
    bf16* Wslot = xb + (size_t)MTOK * HIDDIM;
    size_t need_fast = need_base +
        ((size_t)MTOK * HIDDIM + (size_t)3072 * HIDDIM) * sizeof(bf16);

    if (ws_size < need_base) {
        fill_kernel<<<(out_size + 255) / 256, 256, 0, stream>>>(out, out_size, 1e9f);
        return;
    }

    dim3 blk(256);
    const bool fast = (ws_size >= need_fast);

    if (fast) {
        // pre-convert x and weights (just-in-time into shared slot)
        cvt_bf16<<<2048, blk, 0, stream>>>(x, xb, MTOK * HIDDIM);
        // q
        cvt_bf16<<<1024, blk, 0, stream>>>(Wq, Wslot, 1536 * HIDDIM);
        mfma_gemm_bb<bf16><<<dim3(12, 64), blk, 0, stream>>>(xb, Wslot, wsA, MTOK, 1536, HIDDIM);
        convnorm_qk<<<MTOK * NH, dim3(DKk), 0, stream>>>(wsA, cwq, qb, 0.0625f);
        // k
        cvt_bf16<<<1024, blk, 0, stream>>>(Wk, Wslot, 1536 * HIDDIM);
        mfma_gemm_bb<bf16><<<dim3(12, 64), blk, 0, stream>>>(xb, Wslot, wsA, MTOK, 1536, HIDDIM);
        convnorm_qk<<<MTOK * NH, dim3(DKk), 0, stream>>>(wsA, cwk, kb, 1.0f);
        // v
        cvt_bf16<<<2048, blk, 0, stream>>>(Wv, Wslot, 3072 * HIDDIM);
        mfma_gemm_bb<bf16><<<dim3(24, 64), blk, 0, stream>>>(xb, Wslot, wsB, MTOK, 3072, HIDDIM);
        conv_v_kernel<<<(MTOK * 3072) / 256, blk, 0, stream>>>(wsB, cwv, wsA);
        // beta / g
        proj_ab<<<MTOK, blk, 0, stream>>>(x, Wb, Wa, A_log, dt_bias, betab, gb);
        // chunked delta rule
        chunk_prep<<<NBb * NH * NCH, blk, 0, stream>>>(qb, kb, wsA, wsB, gb, betab, Bmat, scl);
        chunk_scan3<<<NBb * NH * 4, dim3(512), 0, stream>>>(qb, wsA, wsB, Bmat, scl);
        // gate
        cvt_bf16<<<2048, blk, 0, stream>>>(Wg, Wslot, 3072 * HIDDIM);
        mfma_gemm_bb<bf16><<<dim3(24, 64), blk, 0, stream>>>(xb, Wslot, wsA, MTOK, 3072, HIDDIM);
        rmsgate_kernel<<<MTOK * NH, blk, 0, stream>>>(wsB, wsA, norm_w);
        // output projection
        cvt_bf16<<<2048, blk, 0, stream>>>(Wo, Wslot, 2048 * 3072);
        mfma_gemm_bb<float><<<dim3(16, 64), blk, 0, stream>>>(wsB, Wslot, out, MTOK, 2048, 3072);
    } else {
        // fallback: exact round-9 sequence
        mfma_gemm_nt<float, bf16><<<dim3(12, 64), blk, 0, stream>>>(x, Wq, wsA, MTOK, 1536, HIDDIM);
        convnorm_qk<<<MTOK * NH, dim3(DKk), 0, stream>>>(wsA, cwq, qb, 0.0625f);
        mfma_gemm_nt<float, bf16><<<dim3(12, 64), blk, 0, stream>>>(x, Wk, wsA, MTOK, 1536, HIDDIM);
        convnorm_qk<<<MTOK * NH, dim3(DKk), 0, stream>>>(wsA, cwk, kb, 1.0f);
        mfma_gemm_nt<float, bf16><<<dim3(24, 64), blk, 0, stream>>>(x, Wv, wsB, MTOK, 3072, HIDDIM);
        conv_v_kernel<<<(MTOK * 3072) / 256, blk, 0, stream>>>(wsB, cwv, wsA);
        proj_ab<<<MTOK, blk, 0, stream>>>(x, Wb, Wa, A_log, dt_bias, betab, gb);
        chunk_prep<<<NBb * NH * NCH, blk, 0, stream>>>(qb, kb, wsA, wsB, gb, betab, Bmat, scl);
        chunk_scan3<<<NBb * NH * 4, dim3(512), 0, stream>>>(qb, wsA, wsB, Bmat, scl);
        mfma_gemm_nt<float, bf16><<<dim3(24, 64), blk, 0, stream>>>(x, Wg, wsA, MTOK, 3072, HIDDIM);
        rmsgate_kernel<<<MTOK * NH, blk, 0, stream>>>(wsB, wsA, norm_w);
        mfma_gemm_nt<bf16, float><<<dim3(16, 64), blk, 0, stream>>>(wsB, Wo, out, MTOK, 2048, 3072);
    }
}

// Round 12
// 1838.158 us; speedup vs baseline: 1.7170x; 1.0055x over previous
//
#include <hip/hip_runtime.h>
#include <hip/hip_bf16.h>
#include <math.h>

#define NH 6
#define DKk 256
#define DVv 512
#define HIDDIM 2048
#define TT 4096
#define NBb 2
#define MTOK (NBb*TT)   // 8192
#define CH 64
#define NCH (TT/CH)     // 64 chunks per sequence
#define SCLN 136

typedef __hip_bfloat16 bf16;
typedef __attribute__((ext_vector_type(8))) short bf16x8;
typedef __attribute__((ext_vector_type(4))) float f32x4;

union FragU { bf16x8 v; uint2 u2[2]; uint4 u4; };
union BfBits { bf16 h; unsigned short s; };
union U4S8 { uint4 u; unsigned short s[8]; };

__device__ inline float bflo(unsigned u) { return __uint_as_float(u << 16); }
__device__ inline float bfhi(unsigned u) { return __uint_as_float(u & 0xffff0000u); }
__device__ inline unsigned short bfbits(float f) {
    BfBits b; b.h = __float2bfloat16(f); return b.s;
}
__device__ inline float bf2f(unsigned short s) { return __uint_as_float(((unsigned)s) << 16); }
__device__ inline uint4 pack8(float4 a, float4 b) {
    U4S8 r;
    r.s[0] = bfbits(a.x); r.s[1] = bfbits(a.y); r.s[2] = bfbits(a.z); r.s[3] = bfbits(a.w);
    r.s[4] = bfbits(b.x); r.s[5] = bfbits(b.y); r.s[6] = bfbits(b.z); r.s[7] = bfbits(b.w);
    return r.u;
}
__device__ inline uint2 packh4(float a, float b, float c, float d) {
    union { unsigned short s[4]; uint2 u; } r;
    r.s[0] = bfbits(a); r.s[1] = bfbits(b); r.s[2] = bfbits(c); r.s[3] = bfbits(d);
    return r.u;
}
// pack two f32x4 C-tiles (same lane) into a bf16x8 B-frag (C-tile->B-frag identity)
__device__ inline bf16x8 pk8t(f32x4 a, f32x4 b) {
    U4S8 r;
    r.s[0] = bfbits(a[0]); r.s[1] = bfbits(a[1]); r.s[2] = bfbits(a[2]); r.s[3] = bfbits(a[3]);
    r.s[4] = bfbits(b[0]); r.s[5] = bfbits(b[1]); r.s[6] = bfbits(b[2]); r.s[7] = bfbits(b[3]);
    FragU f; f.u4 = r.u; return f.v;
}

// async global->LDS, 16B per lane (LDS dest = wave-uniform base + lane*16)
typedef const __attribute__((address_space(1))) void* gas_ptr;
typedef __attribute__((address_space(3))) void* las_ptr;
__device__ inline void gld16(const void* g, void* s) {
    __builtin_amdgcn_global_load_lds((gas_ptr)g, (las_ptr)s, 16, 0, 0);
}

// LDS tile stride 256 elems, XOR-swizzled by ((row&7)<<4) on byte offset
__device__ inline bf16x8 lfrag256(const short* sh, int n0, int k0) {
    int lane = threadIdx.x & 63;
    int r = n0 + (lane & 15);
    int c = k0 + ((lane >> 4) * 4);
    FragU f;
    f.u2[0] = *(const uint2*)((const char*)sh + (((r * 256 + c) * 2) ^ ((r & 7) << 4)));
    f.u2[1] = *(const uint2*)((const char*)sh + (((r * 256 + c + 16) * 2) ^ ((r & 7) << 4)));
    return f.v;
}
// LDS tile stride 64 elems, swizzled
__device__ inline bf16x8 lfrag64(const short* sh, int n0, int k0) {
    int lane = threadIdx.x & 63;
    int r = n0 + (lane & 15);
    int c = k0 + ((lane >> 4) * 4);
    FragU f;
    f.u2[0] = *(const uint2*)((const char*)sh + (((r * 64 + c) * 2) ^ ((r & 7) << 4)));
    f.u2[1] = *(const uint2*)((const char*)sh + (((r * 64 + c + 16) * 2) ^ ((r & 7) << 4)));
    return f.v;
}
// LDS tile stride 72 elems (padded), no swizzle
__device__ inline bf16x8 lfrag72(const short* sh, int n0, int k0) {
    int lane = threadIdx.x & 63;
    int r = n0 + (lane & 15);
    int c = k0 + ((lane >> 4) * 4);
    FragU f;
    f.u2[0] = *(const uint2*)((const char*)sh + (r * 72 + c) * 2);
    f.u2[1] = *(const uint2*)((const char*)sh + (r * 72 + c + 16) * 2);
    return f.v;
}
// A-frag from f32 [64][68] LDS, scaled per-column, cvt to bf16
__device__ inline bf16x8 mfrag(const float* Msh, const float* colscale, int m0, int k0) {
    int lane = threadIdx.x & 63;
    int t = m0 + (lane & 15);
    int s0 = k0 + ((lane >> 4) * 4);
    U4S8 r;
#pragma unroll
    for (int i = 0; i < 4; ++i) {
        r.s[i]     = bfbits(Msh[t * 68 + s0 + i]      * colscale[s0 + i]);
        r.s[4 + i] = bfbits(Msh[t * 68 + s0 + 16 + i] * colscale[s0 + 16 + i]);
    }
    FragU f; f.u4 = r.u; return f.v;
}

// ---------------------------------------------------------------------------
// fp32 -> bf16 conversion (vectorized, grid-stride). n % 4 == 0.
// ---------------------------------------------------------------------------
__global__ __launch_bounds__(256) void cvt_bf16(const float* __restrict__ in,
                                                bf16* __restrict__ out, int n) {
    for (int i = (blockIdx.x * 256 + threadIdx.x) * 4; i < n; i += gridDim.x * 256 * 4) {
        float4 v = *(const float4*)(in + i);
        *(uint2*)(out + i) = packh4(v.x, v.y, v.z, v.w);
    }
}

// ---------------------------------------------------------------------------
// FAST GEMM (both operands bf16): m97 structure, global_load_lds width-16,
// linear LDS, contiguous-k permutation (identical A/B -> invariant).
// ---------------------------------------------------------------------------
template <typename TC>
__global__ __launch_bounds__(256) void mfma_gemm_bb(const bf16* __restrict__ A,
                                                    const bf16* __restrict__ B,
                                                    TC* __restrict__ C,
                                                    int M, int N, int K) {
    __shared__ __align__(16) short As[128 * 64];
    __shared__ __align__(16) short Bs[128 * 64];
    const int tid = threadIdx.x;
    const int lane = tid & 63;
    const int wid = tid >> 6;
    const int wr = wid >> 1, wc = wid & 1;
    const int bm = blockIdx.y * 128, bn = blockIdx.x * 128;

    f32x4 acc[4][4];
#pragma unroll
    for (int i = 0; i < 4; ++i)
#pragma unroll
        for (int j = 0; j < 4; ++j) acc[i][j] = f32x4{0.f, 0.f, 0.f, 0.f};

    for (int k0 = 0; k0 < K; k0 += 64) {
        __syncthreads();
#pragma unroll
        for (int i = 0; i < 4; ++i) {
            int r0 = wid * 32 + i * 8;
            const bf16* ga = A + (size_t)(bm + r0 + (lane >> 3)) * K + k0 + (lane & 7) * 8;
            const bf16* gb = B + (size_t)(bn + r0 + (lane >> 3)) * K + k0 + (lane & 7) * 8;
            gld16(ga, &As[r0 * 64]);
            gld16(gb, &Bs[r0 * 64]);
        }
        __syncthreads();
#pragma unroll
        for (int kk = 0; kk < 2; ++kk) {
            bf16x8 af[4], bfr[4];
#pragma unroll
            for (int i = 0; i < 4; ++i) {
                FragU f;
                f.u4 = *(const uint4*)&As[(wr * 64 + i * 16 + (lane & 15)) * 64 +
                                          kk * 32 + (lane >> 4) * 8];
                af[i] = f.v;
            }
#pragma unroll
            for (int j = 0; j < 4; ++j) {
                FragU f;
                f.u4 = *(const uint4*)&Bs[(wc * 64 + j * 16 + (lane & 15)) * 64 +
                                          kk * 32 + (lane >> 4) * 8];
                bfr[j] = f.v;
            }
#pragma unroll
            for (int i = 0; i < 4; ++i)
#pragma unroll
                for (int j = 0; j < 4; ++j)
                    acc[i][j] = __builtin_amdgcn_mfma_f32_16x16x32_bf16(
                        af[i], bfr[j], acc[i][j], 0, 0, 0);
        }
    }
#pragma unroll
    for (int i = 0; i < 4; ++i)
#pragma unroll
        for (int j = 0; j < 4; ++j) {
            int row = bm + wr * 64 + i * 16 + (lane >> 4) * 4;
            int col = bn + wc * 64 + j * 16 + (lane & 15);
#pragma unroll
            for (int qi = 0; qi < 4; ++qi) {
                float vv = acc[i][j][qi];
                if constexpr (sizeof(TC) == 2)
                    C[(size_t)(row + qi) * N + col] = __float2bfloat16(vv);
                else
                    C[(size_t)(row + qi) * N + col] = vv;
            }
        }
}

// ---------------------------------------------------------------------------
// FALLBACK GEMM (fp32 B, reg-staged + pack) — round-9 proven.
// ---------------------------------------------------------------------------
template <typename TA, typename TC>
__global__ __launch_bounds__(256) void mfma_gemm_nt(const TA* __restrict__ A,
                                                    const float* __restrict__ B,
                                                    TC* __restrict__ C,
                                                    int M, int N, int K) {
    __shared__ __align__(16) short As[128 * 64];
    __shared__ __align__(16) short Bs[128 * 64];
    const int tid = threadIdx.x;
    const int lane = tid & 63;
    const int wid = tid >> 6;
    const int wr = wid >> 1, wc = wid & 1;
    const int bm = blockIdx.y * 128, bn = blockIdx.x * 128;
    const int srow = tid >> 1;
    const int sks = (tid & 1) * 32;

    f32x4 acc[4][4];
#pragma unroll
    for (int i = 0; i < 4; ++i)
#pragma unroll
        for (int j = 0; j < 4; ++j) acc[i][j] = f32x4{0.f, 0.f, 0.f, 0.f};

    auto swzb = [](int row, int kelem) {
        return ((row * 64 + kelem) * 2) ^ ((row & 7) << 4);
    };
    uint4 ra[4], rb[4];
    auto fetch = [&](int k0) {
        if constexpr (sizeof(TA) == 2) {
            const uint4* pa = (const uint4*)(A + (size_t)(bm + srow) * K + k0 + sks);
#pragma unroll
            for (int j = 0; j < 4; ++j) ra[j] = pa[j];
        } else {
            const float4* pa = (const float4*)(A + (size_t)(bm + srow) * K + k0 + sks);
#pragma unroll
            for (int j = 0; j < 4; ++j) ra[j] = pack8(pa[2 * j], pa[2 * j + 1]);
        }
        const float4* pb = (const float4*)(B + (size_t)(bn + srow) * K + k0 + sks);
#pragma unroll
        for (int j = 0; j < 4; ++j) rb[j] = pack8(pb[2 * j], pb[2 * j + 1]);
    };
    auto store_lds = [&]() {
#pragma unroll
        for (int j = 0; j < 4; ++j) {
            int byte = swzb(srow, sks + 8 * j);
            *(uint4*)((char*)As + byte) = ra[j];
            *(uint4*)((char*)Bs + byte) = rb[j];
        }
    };
    auto rdfrag = [&](const short* Sm, int row, int kbase) {
        FragU f;
        int ko = kbase + (lane >> 4) * 4;
        f.u2[0] = *(const uint2*)((const char*)Sm + swzb(row, ko));
        f.u2[1] = *(const uint2*)((const char*)Sm + swzb(row, ko + 16));
        return f.v;
    };

    fetch(0);
    for (int k0 = 0; k0 < K; k0 += 64) {
        __syncthreads();
        store_lds();
        __syncthreads();
        if (k0 + 64 < K) fetch(k0 + 64);
#pragma unroll
        for (int kk = 0; kk < 2; ++kk) {
            bf16x8 af[4], bfr[4];
#pragma unroll
            for (int i = 0; i < 4; ++i)
                af[i] = rdfrag(As, wr * 64 + i * 16 + (lane & 15), kk * 32);
#pragma unroll
            for (int j = 0; j < 4; ++j)
                bfr[j] = rdfrag(Bs, wc * 64 + j * 16 + (lane & 15), kk * 32);
#pragma unroll
            for (int i = 0; i < 4; ++i)
#pragma unroll
                for (int j = 0; j < 4; ++j)
                    acc[i][j] = __builtin_amdgcn_mfma_f32_16x16x32_bf16(
                        af[i], bfr[j], acc[i][j], 0, 0, 0);
        }
    }
#pragma unroll
    for (int i = 0; i < 4; ++i)
#pragma unroll
        for (int j = 0; j < 4; ++j) {
            int row = bm + wr * 64 + i * 16 + (lane >> 4) * 4;
            int col = bn + wc * 64 + j * 16 + (lane & 15);
#pragma unroll
            for (int qi = 0; qi < 4; ++qi) {
                float vv = acc[i][j][qi];
                if constexpr (sizeof(TC) == 2)
                    C[(size_t)(row + qi) * N + col] = __float2bfloat16(vv);
                else
                    C[(size_t)(row + qi) * N + col] = vv;
            }
        }
}

// ---------------------------------------------------------------------------
// causal depthwise conv4 + SiLU + per-head l2norm (+scale) for q/k.
// ---------------------------------------------------------------------------
__global__ __launch_bounds__(256) void convnorm_qk(const bf16* __restrict__ pre,
                                                   const float* __restrict__ cw,
                                                   bf16* __restrict__ out,
                                                   float scale) {
    const int bth = blockIdx.x;
    const int h = bth % NH;
    const int bt = bth / NH;
    const int t = bt % TT;
    const int d = threadIdx.x;
    const int c = h * DKk + d;
    const int C = NH * DKk;
    const bf16* p = pre + (size_t)bt * C + c;

    float w0 = cw[c * 4 + 0], w1 = cw[c * 4 + 1], w2 = cw[c * 4 + 2], w3 = cw[c * 4 + 3];
    float y = w3 * __bfloat162float(p[0]);
    if (t >= 1) y = fmaf(w2, __bfloat162float(p[-(ptrdiff_t)C]), y);
    if (t >= 2) y = fmaf(w1, __bfloat162float(p[-(ptrdiff_t)(2 * C)]), y);
    if (t >= 3) y = fmaf(w0, __bfloat162float(p[-(ptrdiff_t)(3 * C)]), y);
    y = y / (1.f + expf(-y));   // SiLU

    float s = y * y;
#pragma unroll
    for (int off = 32; off >= 1; off >>= 1) s += __shfl_down(s, off, 64);
    __shared__ float red[4];
    if ((threadIdx.x & 63) == 0) red[threadIdx.x >> 6] = s;
    __syncthreads();
    float tot = (red[0] + red[1]) + (red[2] + red[3]);
    out[(size_t)bt * C + c] = __float2bfloat16(y * rsqrtf(tot + 1e-6f) * scale);
}

// ---------------------------------------------------------------------------
// causal depthwise conv4 + SiLU for v.
// ---------------------------------------------------------------------------
__global__ __launch_bounds__(256) void conv_v_kernel(const bf16* __restrict__ pre,
                                                     const float* __restrict__ cw,
                                                     bf16* __restrict__ out) {
    const int C = NH * DVv;
    int idx = blockIdx.x * 256 + threadIdx.x;
    int c = idx % C;
    int bt = idx / C;
    int t = bt % TT;
    const bf16* p = pre + (size_t)bt * C + c;
    float y = cw[c * 4 + 3] * __bfloat162float(p[0]);
    if (t >= 1) y = fmaf(cw[c * 4 + 2], __bfloat162float(p[-(ptrdiff_t)C]), y);
    if (t >= 2) y = fmaf(cw[c * 4 + 1], __bfloat162float(p[-(ptrdiff_t)(2 * C)]), y);
    if (t >= 3) y = fmaf(cw[c * 4 + 0], __bfloat162float(p[-(ptrdiff_t)(3 * C)]), y);
    out[(size_t)bt * C + c] = __float2bfloat16(y / (1.f + expf(-y)));
}

// ---------------------------------------------------------------------------
// beta = sigmoid(x@Wb.T), g = -exp(A_log)*softplus(x@Wa.T + dt_bias)
// ---------------------------------------------------------------------------
__global__ __launch_bounds__(256) void proj_ab(const float* __restrict__ x,
                                               const float* __restrict__ Wb,
                                               const float* __restrict__ Wa,
                                               const float* __restrict__ A_log,
                                               const float* __restrict__ dt_bias,
                                               float* __restrict__ beta,
                                               float* __restrict__ g) {
    const int bt = blockIdx.x;
    const int tid = threadIdx.x;
    const float* xr = x + (size_t)bt * HIDDIM;
    float accb[NH], acca[NH];
#pragma unroll
    for (int h = 0; h < NH; ++h) { accb[h] = 0.f; acca[h] = 0.f; }
    for (int k0 = tid; k0 < HIDDIM; k0 += 256) {
        float xv = xr[k0];
#pragma unroll
        for (int h = 0; h < NH; ++h) {
            accb[h] = fmaf(xv, Wb[h * HIDDIM + k0], accb[h]);
            acca[h] = fmaf(xv, Wa[h * HIDDIM + k0], acca[h]);
        }
    }
#pragma unroll
    for (int h = 0; h < NH; ++h) {
#pragma unroll
        for (int off = 32; off >= 1; off >>= 1) {
            accb[h] += __shfl_down(accb[h], off, 64);
            acca[h] += __shfl_down(acca[h], off, 64);
        }
    }
    __shared__ float redb[NH][4], reda[NH][4];
    int wv = tid >> 6;
    if ((tid & 63) == 0) {
#pragma unroll
        for (int h = 0; h < NH; ++h) { redb[h][wv] = accb[h]; reda[h][wv] = acca[h]; }
    }
    __syncthreads();
    if (tid < NH) {
        float sb = (redb[tid][0] + redb[tid][1]) + (redb[tid][2] + redb[tid][3]);
        float sa = (reda[tid][0] + reda[tid][1]) + (reda[tid][2] + reda[tid][3]);
        beta[(size_t)bt * NH + tid] = 1.f / (1.f + expf(-sb));
        float xg = sa + dt_bias[tid];
        float sp = fmaxf(xg, 0.f) + log1pf(expf(-fabsf(xg)));
        g[(size_t)bt * NH + tid] = -expf(A_log[tid]) * sp;
    }
}

// ---------------------------------------------------------------------------
// CHUNK PREP (parallel over all 768 (b,h,chunk)) — unchanged.
// ---------------------------------------------------------------------------
__global__ __launch_bounds__(256) void chunk_prep(const bf16* __restrict__ qbuf,
                                                  const bf16* __restrict__ kbuf,
                                                  bf16* __restrict__ vbuf,
                                                  bf16* __restrict__ tvbuf,
                                                  const float* __restrict__ gbuf,
                                                  const float* __restrict__ bbuf,
                                                  bf16* __restrict__ Bmat,
                                                  float* __restrict__ scl) {
    __shared__ __align__(16) short Ksh[64 * 256];
    __shared__ __align__(16) short Qsh[64 * 256];   // later: K_T [256][64]
    __shared__ __align__(16) float Ash[64 * 68];    // A, then M (in place)
    __shared__ __align__(16) short Vt[128 * 72];
    __shared__ float Lsh[64], betash[64], lamsh[64], blamsh[64];

    const int blk = blockIdx.x;
    const int c = blk % NCH;
    const int hh = (blk / NCH) % NH;
    const int b = blk / (NCH * NH);
    const int tid = threadIdx.x;
    const int wid = tid >> 6;
    const int lane = tid & 63;
    const int bt0 = b * TT + c * CH;
    const int cid = (b * NH + hh) * NCH + c;

    // stage K,Q (swizzled)
    {
        int r = tid >> 2, c0 = (tid & 3) * 64;
        const uint4* kg = (const uint4*)(kbuf + (size_t)(bt0 + r) * 1536 + hh * 256 + c0);
        const uint4* qg = (const uint4*)(qbuf + (size_t)(bt0 + r) * 1536 + hh * 256 + c0);
#pragma unroll
        for (int j = 0; j < 8; ++j) {
            int byte = ((r * 256 + c0 + j * 8) * 2) ^ ((r & 7) << 4);
            *(uint4*)((char*)Ksh + byte) = kg[j];
            *(uint4*)((char*)Qsh + byte) = qg[j];
        }
    }
    if (tid < 64) {
        float gv = gbuf[(size_t)(bt0 + tid) * NH + hh];
        float bv = bbuf[(size_t)(bt0 + tid) * NH + hh];
        float L = gv;
#pragma unroll
        for (int off = 1; off < 64; off <<= 1) {
            float o = __shfl_up(L, off, 64);
            if (lane >= off) L += o;
        }
        float L63 = __shfl(L, 63, 64);
        float lam = expf(L);
        Lsh[tid] = L; betash[tid] = bv; lamsh[tid] = lam; blamsh[tid] = bv * lam;
        scl[(size_t)cid * SCLN + tid] = expf(L63 - L);
        scl[(size_t)cid * SCLN + 68 + tid] = lam;
        if (tid == 63) scl[(size_t)cid * SCLN + 64] = lam;  // LamC = e^{L63}
    }
    __syncthreads();

    // KK^T and QK^T
    f32x4 akk[4], aqk[4];
#pragma unroll
    for (int n = 0; n < 4; ++n) { akk[n] = f32x4{0,0,0,0}; aqk[n] = f32x4{0,0,0,0}; }
#pragma unroll
    for (int kk = 0; kk < 8; ++kk) {
        bf16x8 aK = lfrag256(Ksh, wid * 16, kk * 32);
        bf16x8 aQ = lfrag256(Qsh, wid * 16, kk * 32);
#pragma unroll
        for (int n = 0; n < 4; ++n) {
            bf16x8 bK = lfrag256(Ksh, n * 16, kk * 32);
            akk[n] = __builtin_amdgcn_mfma_f32_16x16x32_bf16(aK, bK, akk[n], 0, 0, 0);
            aqk[n] = __builtin_amdgcn_mfma_f32_16x16x32_bf16(aQ, bK, aqk[n], 0, 0, 0);
        }
    }
    // A_mat + B_mat (C layout: row=(lane>>4)*4+qi, col=lane&15)
#pragma unroll
    for (int n = 0; n < 4; ++n)
#pragma unroll
        for (int qi = 0; qi < 4; ++qi) {
            int i = wid * 16 + (lane >> 4) * 4 + qi;
            int s = n * 16 + (lane & 15);
            float av = 0.f, bvv = 0.f;
            if (s <= i) {
                float sc2 = expf(Lsh[i] - Lsh[s]);
                if (s < i) av = betash[i] * sc2 * akk[n][qi];
                bvv = sc2 * aqk[n][qi];
            }
            Ash[i * 68 + s] = av;
            Bmat[(size_t)cid * 4096 + i * 64 + s] = __float2bfloat16(bvv);
        }
    __syncthreads();

    // solve M = (I+A)^-1 (wave 0, lane = column)
    if (wid == 0) {
        float mm[64];
        mm[0] = (lane == 0) ? 1.f : 0.f;
#pragma unroll
        for (int t = 1; t < 64; ++t) {
            float a0 = 0.f, a1 = 0.f, a2 = 0.f, a3 = 0.f;
#pragma unroll
            for (int s = 0; s < t; ++s) {
                float Av = Ash[t * 68 + s];
                if ((s & 3) == 0) a0 = fmaf(Av, mm[s], a0);
                else if ((s & 3) == 1) a1 = fmaf(Av, mm[s], a1);
                else if ((s & 3) == 2) a2 = fmaf(Av, mm[s], a2);
                else a3 = fmaf(Av, mm[s], a3);
            }
            mm[t] = ((t == lane) ? 1.f : 0.f) - ((a0 + a1) + (a2 + a3));
        }
#pragma unroll
        for (int t = 0; t < 64; ++t) Ash[t * 68 + lane] = mm[t];
    }
    __syncthreads();

    // Tv = M(bV) in 4 d-quarters of 128
    for (int q = 0; q < 4; ++q) {
        {   // stage V quarter transposed: Vt[d][i]
            int i = tid >> 2, d0 = (tid & 3) * 32;
            const uint4* vg = (const uint4*)(vbuf + (size_t)(bt0 + i) * 3072 + hh * 512 + q * 128 + d0);
#pragma unroll
            for (int jb = 0; jb < 4; ++jb) {
                U4S8 u; u.u = vg[jb];
#pragma unroll
                for (int e = 0; e < 8; ++e)
                    Vt[(d0 + jb * 8 + e) * 72 + i] = (short)u.s[e];
            }
        }
        __syncthreads();
        f32x4 acc[8];
#pragma unroll
        for (int n = 0; n < 8; ++n) acc[n] = f32x4{0,0,0,0};
#pragma unroll
        for (int kk = 0; kk < 2; ++kk) {
            bf16x8 am = mfrag(Ash, betash, wid * 16, kk * 32);
#pragma unroll
            for (int n = 0; n < 8; ++n) {
                bf16x8 bv8 = lfrag72(Vt, n * 16, kk * 32);
                acc[n] = __builtin_amdgcn_mfma_f32_16x16x32_bf16(am, bv8, acc[n], 0, 0, 0);
            }
        }
#pragma unroll
        for (int n = 0; n < 8; ++n)
#pragma unroll
            for (int qi = 0; qi < 4; ++qi) {
                int t = wid * 16 + (lane >> 4) * 4 + qi;
                int d = q * 128 + n * 16 + (lane & 15);
                tvbuf[(size_t)(bt0 + t) * 3072 + hh * 512 + d] = __float2bfloat16(acc[n][qi]);
            }
        __syncthreads();
    }

    // build K_T [256][64] into Qsh (swizzled)
    {
        int j = tid;
        unsigned short rowv[64];
#pragma unroll
        for (int s = 0; s < 64; ++s)
            rowv[s] = *(const unsigned short*)((const char*)Ksh + (((s * 256 + j) * 2) ^ ((s & 7) << 4)));
#pragma unroll
        for (int sb = 0; sb < 8; ++sb) {
            U4S8 u;
#pragma unroll
            for (int e = 0; e < 8; ++e) u.s[e] = rowv[sb * 8 + e];
            *(uint4*)((char*)Qsh + (((j * 64 + sb * 8) * 2) ^ ((j & 7) << 4))) = u.u;
        }
    }
    __syncthreads();

    // Tk = M(b.Lam.K): A = M*blam, B = K_T
    {
        f32x4 acc[16];
#pragma unroll
        for (int n = 0; n < 16; ++n) acc[n] = f32x4{0,0,0,0};
#pragma unroll
        for (int kk = 0; kk < 2; ++kk) {
            bf16x8 am = mfrag(Ash, blamsh, wid * 16, kk * 32);
#pragma unroll
            for (int n = 0; n < 16; ++n) {
                bf16x8 bk = lfrag64(Qsh, n * 16, kk * 32);
                acc[n] = __builtin_amdgcn_mfma_f32_16x16x32_bf16(am, bk, acc[n], 0, 0, 0);
            }
        }
#pragma unroll
        for (int n = 0; n < 16; ++n)
#pragma unroll
            for (int qi = 0; qi < 4; ++qi) {
                int t = wid * 16 + (lane >> 4) * 4 + qi;
                int j = n * 16 + (lane & 15);
                vbuf[(size_t)(bt0 + t) * 3072 + hh * 512 + j] = __float2bfloat16(acc[n][qi]);
            }
    }
    // flush K_T -> global segment layout: row i=j>>2 of chunk, cols 256 + (j&3)*64 + s
    {
        int j = tid;
#pragma unroll
        for (int sb = 0; sb < 8; ++sb) {
            uint4 u = *(uint4*)((char*)Qsh + (((j * 64 + sb * 8) * 2) ^ ((j & 7) << 4)));
            *(uint4*)(vbuf + (size_t)(bt0 + (j >> 2)) * 3072 + hh * 512 + 256 + (j & 3) * 64 + sb * 8) = u;
        }
    }
}

// ---------------------------------------------------------------------------
// CHUNK SCAN v5 — same math as v3, spread over 4x more CUs.
// 192 blocks = 12 bh x 16 parts, 128 threads = 2 waves; wave w owns slice
// part*2+w (16 DV cols). Each block stages the full Tk/Q/KT/Bmat (104KB)
// into its own LDS (L2 serves the duplicate streams); per-CU LDS/MFMA pipe
// work drops 4x vs v3 (ds_reads 1360->340, MFMA 900->224 per CU per chunk).
// ---------------------------------------------------------------------------
__global__ __launch_bounds__(128, 1) void chunk_scan5(const bf16* __restrict__ qbuf,
                                                      const bf16* __restrict__ vbuf,
                                                      bf16* __restrict__ tvbuf,
                                                      const bf16* __restrict__ Bmat,
                                                      const float* __restrict__ scl) {
    __shared__ __align__(16) short TkL[64 * 256];   // 32KB, lfrag256 layout
    __shared__ __align__(16) short QL[64 * 256];    // 32KB, lfrag256
    __shared__ __align__(16) short KTL[256 * 64];   // 32KB, lfrag64
    __shared__ __align__(16) short BmL[64 * 64];    // 8KB,  lfrag64
    const int tid = threadIdx.x;
    const int wid = tid >> 6;                    // 0..1
    const int lane = tid & 63;
    const int part = blockIdx.x & 15;            // 0..15
    const int bh = blockIdx.x >> 4;
    const int hh = bh % NH;
    const int b = bh / NH;
    const int slice = part * 2 + wid;            // 0..31
    const int dglob0 = hh * 512 + slice * 16;
    const int tlo = (lane >> 4) * 4;
    const int dcol = lane & 15;

    f32x4 S[16];
#pragma unroll
    for (int i = 0; i < 16; ++i) S[i] = f32x4{0.f, 0.f, 0.f, 0.f};

    for (int c = 0; c < NCH; ++c) {
        const int bt0 = b * TT + c * CH;
        const int cid = (b * NH + hh) * NCH + c;
        const float* sc = scl + (size_t)cid * SCLN;
        const float lamC = sc[64];

        __syncthreads();   // prior chunk's LDS reads complete
        // ---- stage Tk (64x256, vbuf cols [0,256)) and Q (64x256, qbuf) ----
        {
            int r = tid >> 1;                    // 0..63
            int bc0 = (tid & 1) * 16;
#pragma unroll
            for (int rd = 0; rd < 16; ++rd) {
                int bc = bc0 + rd * 32;          // byte col in [0,512)
                uint4 tv = *(const uint4*)((const char*)(vbuf) +
                    ((size_t)(bt0 + r) * 3072 + hh * 512) * 2 + bc);
                uint4 qv = *(const uint4*)((const char*)(qbuf) +
                    ((size_t)(bt0 + r) * 1536 + hh * 256) * 2 + bc);
                int byte = (r * 512 + bc) ^ ((r & 7) << 4);
                *(uint4*)((char*)TkL + byte) = tv;
                *(uint4*)((char*)QL + byte) = qv;
            }
        }
        // ---- stage KT (256x64 = 128B/row, vbuf cols [256,512) packed) ----
        {
#pragma unroll
            for (int rr = 0; rr < 2; ++rr) {
                int j = tid * 2 + rr;            // 0..255
#pragma unroll
                for (int rd = 0; rd < 8; ++rd) {
                    int bc = rd * 16;            // byte col in [0,128)
                    uint4 v = *(const uint4*)((const char*)(vbuf) +
                        ((size_t)(bt0 + (j >> 2)) * 3072 + hh * 512 + 256 + (j & 3) * 64) * 2 + bc);
                    int byte = (j * 128 + bc) ^ ((j & 7) << 4);
                    *(uint4*)((char*)KTL + byte) = v;
                }
            }
        }
        // ---- stage Bmat (64 rows x 128B) ----
        {
            int r = tid >> 1;
            int bc0 = (tid & 1) * 16;
#pragma unroll
            for (int rd = 0; rd < 4; ++rd) {
                int bc = bc0 + rd * 32;
                uint4 v = *(const uint4*)((const char*)(Bmat) +
                    ((size_t)cid * 4096 + r * 64) * 2 + bc);
                int byte = (r * 128 + bc) ^ ((r & 7) << 4);
                *(uint4*)((char*)BmL + byte) = v;
            }
        }
        __syncthreads();

        // ---- per-wave register-only math (identical to v3) ----
        bf16x8 sfr[8];
#pragma unroll
        for (int kk = 0; kk < 8; ++kk) sfr[kk] = pk8t(S[2 * kk], S[2 * kk + 1]);

        f32x4 P[4], O[4];
#pragma unroll
        for (int tf = 0; tf < 4; ++tf) { P[tf] = f32x4{0,0,0,0}; O[tf] = f32x4{0,0,0,0}; }
#pragma unroll
        for (int tf = 0; tf < 4; ++tf)
#pragma unroll
            for (int kk = 0; kk < 8; ++kk) {
                bf16x8 aT = lfrag256(TkL, tf * 16, kk * 32);
                bf16x8 aQ = lfrag256(QL, tf * 16, kk * 32);
                P[tf] = __builtin_amdgcn_mfma_f32_16x16x32_bf16(aT, sfr[kk], P[tf], 0, 0, 0);
                O[tf] = __builtin_amdgcn_mfma_f32_16x16x32_bf16(aQ, sfr[kk], O[tf], 0, 0, 0);
            }
        // O *= lam_t ; U = Tv - P (in place over P)
#pragma unroll
        for (int tf = 0; tf < 4; ++tf) {
            float4 lam4 = *(const float4*)(sc + 68 + tf * 16 + tlo);
            O[tf][0] *= lam4.x; O[tf][1] *= lam4.y; O[tf][2] *= lam4.z; O[tf][3] *= lam4.w;
            int t = tf * 16 + tlo;
#pragma unroll
            for (int qi = 0; qi < 4; ++qi) {
                float tv = __bfloat162float(tvbuf[(size_t)(bt0 + t + qi) * 3072 + dglob0 + dcol]);
                P[tf][qi] = tv - P[tf][qi];
            }
        }
        bf16x8 ufr0 = pk8t(P[0], P[1]);
        bf16x8 ufr1 = pk8t(P[2], P[3]);
#pragma unroll
        for (int tf = 0; tf < 4; ++tf) {
            bf16x8 aB0 = lfrag64(BmL, tf * 16, 0);
            bf16x8 aB1 = lfrag64(BmL, tf * 16, 32);
            O[tf] = __builtin_amdgcn_mfma_f32_16x16x32_bf16(aB0, ufr0, O[tf], 0, 0, 0);
            O[tf] = __builtin_amdgcn_mfma_f32_16x16x32_bf16(aB1, ufr1, O[tf], 0, 0, 0);
            int t = tf * 16 + tlo;
#pragma unroll
            for (int qi = 0; qi < 4; ++qi)
                tvbuf[(size_t)(bt0 + t + qi) * 3072 + dglob0 + dcol] = __float2bfloat16(O[tf][qi]);
        }
        // Ut B-frags: eC_t o U
        bf16x8 utfr[2];
#pragma unroll
        for (int k2 = 0; k2 < 2; ++k2) {
            float4 e0 = *(const float4*)(sc + k2 * 32 + tlo);
            float4 e1 = *(const float4*)(sc + k2 * 32 + 16 + tlo);
            f32x4 ua = P[2 * k2], ub = P[2 * k2 + 1];
            ua[0] *= e0.x; ua[1] *= e0.y; ua[2] *= e0.z; ua[3] *= e0.w;
            ub[0] *= e1.x; ub[1] *= e1.y; ub[2] *= e1.z; ub[3] *= e1.w;
            utfr[k2] = pk8t(ua, ub);
        }
        // S = lamC*S + KT.(eC o U)
#pragma unroll
        for (int kt = 0; kt < 16; ++kt) {
            S[kt][0] *= lamC; S[kt][1] *= lamC; S[kt][2] *= lamC; S[kt][3] *= lamC;
        }
#pragma unroll
        for (int kt = 0; kt < 16; ++kt)
#pragma unroll
            for (int k2 = 0; k2 < 2; ++k2) {
                bf16x8 aK = lfrag64(KTL, kt * 16, k2 * 32);
                S[kt] = __builtin_amdgcn_mfma_f32_16x16x32_bf16(aK, utfr[k2], S[kt], 0, 0, 0);
            }
    }
}

// ---------------------------------------------------------------------------
// per-head RMSNorm (eps 1e-5) * norm_w, then * silu(gate). In-place (bf16).
// ---------------------------------------------------------------------------
__global__ __launch_bounds__(256) void rmsgate_kernel(bf16* __restrict__ o,
                                                      const bf16* __restrict__ gate,
                                                      const float* __restrict__ norm_w) {
    const int bhead = blockIdx.x;
    const int d = threadIdx.x;
    bf16* op = o + (size_t)bhead * DVv;
    const bf16* gp = gate + (size_t)bhead * DVv;
    float x0 = __bfloat162float(op[d]), x1 = __bfloat162float(op[d + 256]);
    float s = x0 * x0 + x1 * x1;
#pragma unroll
    for (int off = 32; off >= 1; off >>= 1) s += __shfl_down(s, off, 64);
    __shared__ float red[4];
    if ((threadIdx.x & 63) == 0) red[threadIdx.x >> 6] = s;
    __syncthreads();
    float tot = (red[0] + red[1]) + (red[2] + red[3]);
    float r = rsqrtf(tot * (1.f / DVv) + 1e-5f);
    float g0 = __bfloat162float(gp[d]), g1 = __bfloat162float(gp[d + 256]);
    g0 = g0 / (1.f + expf(-g0));
    g1 = g1 / (1.f + expf(-g1));
    op[d]       = __float2bfloat16(x0 * r * norm_w[d] * g0);
    op[d + 256] = __float2bfloat16(x1 * r * norm_w[d + 256] * g1);
}

__global__ void fill_kernel(float* p, int n, float v) {
    int i = blockIdx.x * 256 + threadIdx.x;
    if (i < n) p[i] = v;
}

// ---------------------------------------------------------------------------
extern "C" void kernel_launch(void* const* d_in, const int* in_sizes, int n_in,
                              void* d_out, int out_size, void* d_ws, size_t ws_size,
                              hipStream_t stream) {
    const float* x       = (const float*)d_in[0];
    const float* Wq      = (const float*)d_in[1];
    const float* Wk      = (const float*)d_in[2];
    const float* Wv      = (const float*)d_in[3];
    const float* Wb      = (const float*)d_in[4];
    const float* Wa      = (const float*)d_in[5];
    const float* A_log   = (const float*)d_in[6];
    const float* dt_bias = (const float*)d_in[7];
    const float* cwq     = (const float*)d_in[8];
    const float* cwk     = (const float*)d_in[9];
    const float* cwv     = (const float*)d_in[10];
    const float* Wg      = (const float*)d_in[11];
    const float* norm_w  = (const float*)d_in[12];
    const float* Wo      = (const float*)d_in[13];
    float* out = (float*)d_out;

    // d_out scratch: qb/kb ONLY (write-once-read-later, replay-proven).
    bf16* qb = (bf16*)d_out;                          // [8192,1536]
    bf16* kb = qb + (size_t)MTOK * 1536;              // [8192,1536]

    // ws base layout (round-9 proven):
    const size_t elemsA = (size_t)MTOK * 3072;
    const size_t elemsB = (size_t)MTOK * 3072;
    bf16* wsA   = (bf16*)d_ws;
    bf16* wsB   = wsA + elemsA;
    bf16* Bmat  = wsB + elemsB;                       // [768][64][64]
    float* scl  = (float*)(Bmat + (size_t)NBb * NH * NCH * 4096);  // [768][136]
    float* betab = scl + (size_t)NBb * NH * NCH * SCLN;
    float* gb    = betab + (size_t)MTOK * NH;
    size_t need_base = ((size_t)(gb - (float*)d_ws) + (size_t)MTOK * NH) * sizeof(float);
    // fast-path extras: bf16 x + one shared weight slot (lifetimes disjoint)
    bf16* xb    = (bf16*)(gb + (size_t)MTOK * NH);
    bf16* Wslot = xb + (size_t)MTOK * HIDDIM;
    size_t need_fast = need_base +
        ((size_t)MTOK * HIDDIM + (size_t)3072 * HIDDIM) * sizeof(bf16);

    if (ws_size < need_base) {
        fill_kernel<<<(out_size + 255) / 256, 256, 0, stream>>>(out, out_size, 1e9f);
        return;
    }

    dim3 blk(256);
    const bool fast = (ws_size >= need_fast);

    if (fast) {
        cvt_bf16<<<2048, blk, 0, stream>>>(x, xb, MTOK * HIDDIM);
        // q
        cvt_bf16<<<1024, blk, 0, stream>>>(Wq, Wslot, 1536 * HIDDIM);
        mfma_gemm_bb<bf16><<<dim3(12, 64), blk, 0, stream>>>(xb, Wslot, wsA, MTOK, 1536, HIDDIM);
        convnorm_qk<<<MTOK * NH, dim3(DKk), 0, stream>>>(wsA, cwq, qb, 0.0625f);
        // k
        cvt_bf16<<<1024, blk, 0, stream>>>(Wk, Wslot, 1536 * HIDDIM);
        mfma_gemm_bb<bf16><<<dim3(12, 64), blk, 0, stream>>>(xb, Wslot, wsA, MTOK, 1536, HIDDIM);
        convnorm_qk<<<MTOK * NH, dim3(DKk), 0, stream>>>(wsA, cwk, kb, 1.0f);
        // v
        cvt_bf16<<<2048, blk, 0, stream>>>(Wv, Wslot, 3072 * HIDDIM);
        mfma_gemm_bb<bf16><<<dim3(24, 64), blk, 0, stream>>>(xb, Wslot, wsB, MTOK, 3072, HIDDIM);
        conv_v_kernel<<<(MTOK * 3072) / 256, blk, 0, stream>>>(wsB, cwv, wsA);
        // beta / g
        proj_ab<<<MTOK, blk, 0, stream>>>(x, Wb, Wa, A_log, dt_bias, betab, gb);
        // chunked delta rule
        chunk_prep<<<NBb * NH * NCH, blk, 0, stream>>>(qb, kb, wsA, wsB, gb, betab, Bmat, scl);
        chunk_scan5<<<NBb * NH * 16, dim3(128), 0, stream>>>(qb, wsA, wsB, Bmat, scl);
        // gate
        cvt_bf16<<<2048, blk, 0, stream>>>(Wg, Wslot, 3072 * HIDDIM);
        mfma_gemm_bb<bf16><<<dim3(24, 64), blk, 0, stream>>>(xb, Wslot, wsA, MTOK, 3072, HIDDIM);
        rmsgate_kernel<<<MTOK * NH, blk, 0, stream>>>(wsB, wsA, norm_w);
        // output projection
        cvt_bf16<<<2048, blk, 0, stream>>>(Wo, Wslot, 2048 * 3072);
        mfma_gemm_bb<float><<<dim3(16, 64), blk, 0, stream>>>(wsB, Wslot, out, MTOK, 2048, 3072);
    } else {
        mfma_gemm_nt<float, bf16><<<dim3(12, 64), blk, 0, stream>>>(x, Wq, wsA, MTOK, 1536, HIDDIM);
        convnorm_qk<<<MTOK * NH, dim3(DKk), 0, stream>>>(wsA, cwq, qb, 0.0625f);
        mfma_gemm_nt<float, bf16><<<dim3(12, 64), blk, 0, stream>>>(x, Wk, wsA, MTOK, 1536, HIDDIM);
        convnorm_qk<<<MTOK * NH, dim3(DKk), 0, stream>>>(wsA, cwk, kb, 1.0f);
        mfma_gemm_nt<float, bf16><<<dim3(24, 64), blk, 0, stream>>>(x, Wv, wsB, MTOK, 3072, HIDDIM);
        conv_v_kernel<<<(MTOK * 3072) / 256, blk, 0, stream>>>(wsB, cwv, wsA);
        proj_ab<<<MTOK, blk, 0, stream>>>(x, Wb, Wa, A_log, dt_bias, betab, gb);
        chunk_prep<<<NBb * NH * NCH, blk, 0, stream>>>(qb, kb, wsA, wsB, gb, betab, Bmat, scl);
        chunk_scan5<<<NBb * NH * 16, dim3(128), 0, stream>>>(qb, wsA, wsB, Bmat, scl);
        mfma_gemm_nt<float, bf16><<<dim3(24, 64), blk, 0, stream>>>(x, Wg, wsA, MTOK, 3072, HIDDIM);
        rmsgate_kernel<<<MTOK * NH, blk, 0, stream>>>(wsB, wsA, norm_w);
        mfma_gemm_nt<bf16, float><<<dim3(16, 64), blk, 0, stream>>>(wsB, Wo, out, MTOK, 2048, 3072);
    }
}